// Round 1
// 4301.344 us; speedup vs baseline: 1.0464x; 1.0464x over previous
//
#include <hip/hip_runtime.h>
#include <math.h>

#define NTOK 65536
#define DMODEL 256
#define DI 512
#define DS 16
#define CHUNK 128
#define NCHUNK (NTOK / CHUNK)   // 512
#define QCH 128                 // channels per scan quarter

typedef __bf16 bf16x8 __attribute__((ext_vector_type(8)));
typedef float  f32x4  __attribute__((ext_vector_type(4)));

__device__ __forceinline__ float sigf(float x) { return 1.0f / (1.0f + expf(-x)); }

__device__ __forceinline__ void bf16split(float x, unsigned short& hi, unsigned short& lo)
{
    union { __bf16 b; unsigned short u; } cv;
    __bf16 h = (__bf16)x;
    cv.b = h; hi = cv.u;
    cv.b = (__bf16)(x - (float)h); lo = cv.u;
}

// ---------------------------------------------------------------------------
// in_conv_kernel: unchanged (round-5 verified)
// ---------------------------------------------------------------------------
__global__ __launch_bounds__(512) void in_conv_kernel(
    const float* x, const float* in_proj_w, const float* conv_w,
    const float* conv_b, float* P1, float* P2)
{
    __shared__ float As[32][72];    // [k][row: 0..3 halo, 4..67 main]
    __shared__ float Wt[32][132];
    __shared__ float xt[68][132];
    const int tid = threadIdx.x;
    const int row0 = blockIdx.x * 64;
    const int tr = (tid & 15) * 4;
    const int tc = (tid >> 4) * 4;
    const int hr = tid >> 7;        // 0..3
    const int hc = tid & 127;       // 0..127

    for (int ct = 0; ct < 8; ct++) {
        float acc[4][4];
#pragma unroll
        for (int i = 0; i < 4; i++)
#pragma unroll
            for (int j = 0; j < 4; j++) acc[i][j] = 0.f;
        float acch = 0.f;
        for (int k0 = 0; k0 < 256; k0 += 32) {
            __syncthreads();
            for (int i = tid; i < 68 * 32; i += 512) {
                int l = i >> 5, k = i & 31;
                int gr = row0 - 4 + l;
                As[k][l] = (gr >= 0) ? x[(size_t)gr * 256 + k0 + k] : 0.f;
            }
            {
                int n = tid >> 2, kq = (tid & 3) * 8;
                const float* wp = in_proj_w + (size_t)(ct * 128 + n) * 256 + k0 + kq;
                float4 w0 = *(const float4*)wp, w1 = *(const float4*)(wp + 4);
                Wt[kq + 0][n] = w0.x; Wt[kq + 1][n] = w0.y;
                Wt[kq + 2][n] = w0.z; Wt[kq + 3][n] = w0.w;
                Wt[kq + 4][n] = w1.x; Wt[kq + 5][n] = w1.y;
                Wt[kq + 6][n] = w1.z; Wt[kq + 7][n] = w1.w;
            }
            __syncthreads();
#pragma unroll 8
            for (int kk = 0; kk < 32; kk++) {
                float4 a = *(const float4*)&As[kk][4 + tr];
                float4 b = *(const float4*)&Wt[kk][tc];
                acc[0][0] += a.x*b.x; acc[0][1] += a.x*b.y; acc[0][2] += a.x*b.z; acc[0][3] += a.x*b.w;
                acc[1][0] += a.y*b.x; acc[1][1] += a.y*b.y; acc[1][2] += a.y*b.z; acc[1][3] += a.y*b.w;
                acc[2][0] += a.z*b.x; acc[2][1] += a.z*b.y; acc[2][2] += a.z*b.z; acc[2][3] += a.z*b.w;
                acc[3][0] += a.w*b.x; acc[3][1] += a.w*b.y; acc[3][2] += a.w*b.z; acc[3][3] += a.w*b.w;
                if (ct < 4) acch += As[kk][hr] * Wt[kk][hc];
            }
        }
        if (ct < 4) {
            __syncthreads();
#pragma unroll
            for (int i = 0; i < 4; i++)
#pragma unroll
                for (int j = 0; j < 4; j++)
                    xt[4 + tr + i][tc + j] = acc[i][j];
            xt[hr][hc] = acch;
            __syncthreads();
#pragma unroll
            for (int i = 0; i < 4; i++) {
                int r = row0 + tr + i;
#pragma unroll
                for (int j = 0; j < 4; j++) {
                    int c = ct * 128 + tc + j;
                    float cv = conv_b[c];
#pragma unroll
                    for (int k = 0; k < 4; k++)
                        cv += conv_w[c * 4 + k] * xt[tr + i + 1 + k][tc + j];
                    P1[(size_t)r * 512 + c] = cv * sigf(cv);
                }
            }
        } else {
#pragma unroll
            for (int i = 0; i < 4; i++) {
                int r = row0 + tr + i;
                float4 zv;
                zv.x = acc[i][0]; zv.y = acc[i][1]; zv.z = acc[i][2]; zv.w = acc[i][3];
                zv.x = zv.x * sigf(zv.x); zv.y = zv.y * sigf(zv.y);
                zv.z = zv.z * sigf(zv.z); zv.w = zv.w * sigf(zv.w);
                *(float4*)&P2[(size_t)r * 512 + (ct - 4) * 128 + tc] = zv;
            }
        }
    }
}

// ---------------------------------------------------------------------------
// wprep_kernel: split the two used 512x512 blocks of gg2_w into hi/lo bf16,
// laid out in exactly the per-chunk staging order of gates_mfma_kernel:
//   packet p (16B = 8 bf16) at Wg + chunk*2048*8 + p*8
//   chunk = ((gm*2 + cb)*16 + kc);  p = hl*1024 + c*4 + (kq/8)
//   element = W[gm*1024 + cb*256 + c][kc*32 + kq + j]   (hi or lo half)
// ---------------------------------------------------------------------------
__global__ __launch_bounds__(256) void wprep_kernel(
    const float* gg2_w, unsigned short* Wg)
{
    int p = blockIdx.x * 256 + threadIdx.x;   // 0 .. 131071
    int chunk = p >> 11;                      // 0..63
    int rem = p & 2047;
    int gm = chunk >> 5;
    int cb = (chunk >> 4) & 1;
    int kc = chunk & 15;
    int hl = rem >> 10;
    int c  = (rem >> 2) & 255;
    int kq = (rem & 3) * 8;
    int row = gm * 1024 + cb * 256 + c;       // gate_in rows 0..512, gate_out 1024..1536
    const float* src = gg2_w + (size_t)row * 512 + kc * 32 + kq;
    union { unsigned short u[8]; float4 f; } outv;
#pragma unroll
    for (int j = 0; j < 8; j++) {
        float v = src[j];
        unsigned short hi, lo;
        bf16split(v, hi, lo);
        outv.u[j] = hl ? lo : hi;
    }
    *(float4*)(Wg + (size_t)p * 8) = outv.f;
}

// ---------------------------------------------------------------------------
// gates_mfma_kernel: bf16x3 split-precision MFMA version of the gate GEMMs.
//   Phase A (unchanged math): g = gelu(LN(guidance @ gg1_w.T + gg1_b)),
//     held in registers: thread (tok=tid&63, o=tid>>6) holds g[d=o+8j], j<64.
//   Phase B: per gm in {gate_in, gate_out}: 64x256 output tile,
//     acc = Ah*Wh + Ah*Wl + Al*Wh   (fp32 MFMA accumulate, K-chunks of 32)
//   8 waves as 2(M) x 4(N); wave tile 32 tokens x 64 cols; 16x16x32 bf16 MFMA.
//   LDS rows padded 32->40 bf16: ds_read_b128 bank-load is uniform (8/bank).
// grid: (NTOK/64, 2 colblocks of 256)
// ---------------------------------------------------------------------------
__global__ __launch_bounds__(512) void gates_mfma_kernel(
    const float* guidance, const float* gg1_w, const float* gg1_b,
    const float* ln_g, const float* ln_b,
    const unsigned short* Wg, const float* gg2_b,
    float* P1, float* P2)
{
    __shared__ unsigned short Wlds[2][256][40];   // [hi/lo][col][k] 40 KiB
    __shared__ unsigned short Alds[2][64][40];    // [hi/lo][tok][k] 10 KiB
    __shared__ float red_s[64][9], red_q[64][9];

    const int tid = threadIdx.x;
    const int tok = tid & 63;
    const int o = tid >> 6;          // 0..7 == wave id
    const int row0 = blockIdx.x * 64;
    const int cb = blockIdx.y;       // 0..1 (256-col block within each gate)

    // ---- Phase A: g into registers (identical math to verified version) ----
    float g0 = guidance[(size_t)(row0 + tok) * 3 + 0];
    float g1 = guidance[(size_t)(row0 + tok) * 3 + 1];
    float g2 = guidance[(size_t)(row0 + tok) * 3 + 2];
    float v[64];
    float sum = 0.f, sumsq = 0.f;
#pragma unroll
    for (int j = 0; j < 64; j++) {
        int d = o + 8 * j;
        float t = gg1_w[d * 3 + 0] * g0 + gg1_w[d * 3 + 1] * g1 +
                  gg1_w[d * 3 + 2] * g2 + gg1_b[d];
        v[j] = t;
        sum += t; sumsq += t * t;
    }
    red_s[tok][o] = sum; red_q[tok][o] = sumsq;
    __syncthreads();
    sum = 0.f; sumsq = 0.f;
#pragma unroll
    for (int oo = 0; oo < 8; oo++) { sum += red_s[tok][oo]; sumsq += red_q[tok][oo]; }
    float mu = sum * (1.f / 512.f);
    float var = fmaxf(sumsq * (1.f / 512.f) - mu * mu, 0.f);
    float rstd = 1.f / sqrtf(var + 1e-5f);
#pragma unroll
    for (int j = 0; j < 64; j++) {
        int d = o + 8 * j;
        float t = (v[j] - mu) * rstd * ln_g[d] + ln_b[d];
        v[j] = 0.5f * t * (1.f + erff(t * 0.70710678118654752440f));
    }

    // ---- Phase B: MFMA GEMMs ----
    const int l  = tid & 63;
    const int wm = o >> 2;           // wave row: 0..1  (32 tokens each)
    const int wn = o & 3;            // wave col: 0..3  (64 cols each)
    const int lr = l & 15;
    const int lg = l >> 4;

    for (int gm = 0; gm < 2; gm++) {
        f32x4 acc[2][4];
#pragma unroll
        for (int fm = 0; fm < 2; fm++)
#pragma unroll
            for (int fn = 0; fn < 4; fn++)
                acc[fm][fn] = (f32x4){0.f, 0.f, 0.f, 0.f};

        for (int kc = 0; kc < 16; kc++) {
            // Issue W loads BEFORE the barrier: latency hides under the
            // other waves finishing the previous chunk's compute.
            const unsigned short* wgc =
                Wg + ((((size_t)gm * 2 + cb) * 16 + kc) * 2048) * 8;
            float4 wv[4];
            int wp[4];
#pragma unroll
            for (int i = 0; i < 4; i++) {
                int p = tid + 512 * i;
                wp[i] = p;
                wv[i] = *(const float4*)(wgc + (size_t)p * 8);
            }
            __syncthreads();
            // A stage: this chunk's 4 g-values per thread, split hi/lo.
            int j0 = kc * 4;
#pragma unroll
            for (int jj = 0; jj < 4; jj++) {
                unsigned short hi, lo;
                bf16split(v[j0 + jj], hi, lo);
                Alds[0][tok][o + 8 * jj] = hi;
                Alds[1][tok][o + 8 * jj] = lo;
            }
            // W stage: 4 x 16B packets per thread.
#pragma unroll
            for (int i = 0; i < 4; i++) {
                int p = wp[i];
                int hl = p >> 10, c = (p >> 2) & 255, kq = (p & 3) * 8;
                *(float4*)&Wlds[hl][c][kq] = wv[i];
            }
            __syncthreads();
            // Fragments + MFMA. a_frag[j] = A[r][k0+lg*8+j],
            // b_frag[j] = B[k0+lg*8+j][c]: same k enumeration both sides.
            bf16x8 ah[2], al[2];
#pragma unroll
            for (int fm = 0; fm < 2; fm++) {
                ah[fm] = *(const bf16x8*)&Alds[0][wm * 32 + fm * 16 + lr][lg * 8];
                al[fm] = *(const bf16x8*)&Alds[1][wm * 32 + fm * 16 + lr][lg * 8];
            }
#pragma unroll
            for (int fn = 0; fn < 4; fn++) {
                bf16x8 wh = *(const bf16x8*)&Wlds[0][wn * 64 + fn * 16 + lr][lg * 8];
                bf16x8 wl = *(const bf16x8*)&Wlds[1][wn * 64 + fn * 16 + lr][lg * 8];
#pragma unroll
                for (int fm = 0; fm < 2; fm++) {
                    acc[fm][fn] = __builtin_amdgcn_mfma_f32_16x16x32_bf16(
                        ah[fm], wh, acc[fm][fn], 0, 0, 0);
                    acc[fm][fn] = __builtin_amdgcn_mfma_f32_16x16x32_bf16(
                        ah[fm], wl, acc[fm][fn], 0, 0, 0);
                    acc[fm][fn] = __builtin_amdgcn_mfma_f32_16x16x32_bf16(
                        al[fm], wh, acc[fm][fn], 0, 0, 0);
                }
            }
        }
        // Epilogue: C/D layout col = lane&15, row = (lane>>4)*4 + reg (m89).
        float* P = gm ? P2 : P1;
        const float* bias = gg2_b + gm * 1024 + cb * 256;
#pragma unroll
        for (int fm = 0; fm < 2; fm++)
#pragma unroll
            for (int fn = 0; fn < 4; fn++) {
                int cl = wn * 64 + fn * 16 + lr;
                float b = bias[cl];
#pragma unroll
                for (int q = 0; q < 4; q++) {
                    int r = row0 + wm * 32 + fm * 16 + lg * 4 + q;
                    size_t idx = (size_t)r * 512 + cb * 256 + cl;
                    P[idx] *= sigf(acc[fm][fn][q] + b);
                }
            }
    }
}

// ---------------------------------------------------------------------------
// gemm512: out = A(N,K) @ W(M,K).T, 64x128 tile, 512 threads, float4 reads.
// EPI 0: plain store   EPI 2: softplus(v + bias[c])
// ---------------------------------------------------------------------------
template <int EPI>
__global__ __launch_bounds__(512) void gemm512(
    const float* A, const float* W, const float* bias,
    float* out0, int K, int ldo, int colbase)
{
    __shared__ float As[32][68];
    __shared__ float Wt[32][132];
    const int tid = threadIdx.x;
    const int row0 = blockIdx.x * 64;
    const int col0 = colbase + blockIdx.y * 128;
    const int tr = (tid & 15) * 4;
    const int tc = (tid >> 4) * 4;
    float acc[4][4];
#pragma unroll
    for (int i = 0; i < 4; i++)
#pragma unroll
        for (int j = 0; j < 4; j++) acc[i][j] = 0.f;

    for (int k0 = 0; k0 < K; k0 += 32) {
        __syncthreads();
        for (int i = tid; i < 64 * 32; i += 512) {
            int l = i >> 5, k = i & 31;
            As[k][l] = A[(size_t)(row0 + l) * K + k0 + k];
        }
        {
            int n = tid >> 2, kq = (tid & 3) * 8;
            const float* wp = W + (size_t)(col0 + n) * K + k0 + kq;
            float4 w0 = *(const float4*)wp, w1 = *(const float4*)(wp + 4);
            Wt[kq + 0][n] = w0.x; Wt[kq + 1][n] = w0.y;
            Wt[kq + 2][n] = w0.z; Wt[kq + 3][n] = w0.w;
            Wt[kq + 4][n] = w1.x; Wt[kq + 5][n] = w1.y;
            Wt[kq + 6][n] = w1.z; Wt[kq + 7][n] = w1.w;
        }
        __syncthreads();
#pragma unroll 8
        for (int kk = 0; kk < 32; kk++) {
            float4 a = *(const float4*)&As[kk][tr];
            float4 b = *(const float4*)&Wt[kk][tc];
            acc[0][0] += a.x*b.x; acc[0][1] += a.x*b.y; acc[0][2] += a.x*b.z; acc[0][3] += a.x*b.w;
            acc[1][0] += a.y*b.x; acc[1][1] += a.y*b.y; acc[1][2] += a.y*b.z; acc[1][3] += a.y*b.w;
            acc[2][0] += a.z*b.x; acc[2][1] += a.z*b.y; acc[2][2] += a.z*b.z; acc[2][3] += a.z*b.w;
            acc[3][0] += a.w*b.x; acc[3][1] += a.w*b.y; acc[3][2] += a.w*b.z; acc[3][3] += a.w*b.w;
        }
    }
#pragma unroll
    for (int i = 0; i < 4; i++) {
        int r = row0 + tr + i;
#pragma unroll
        for (int j = 0; j < 4; j++) {
            int c = col0 + tc + j;
            float vv = acc[i][j];
            if (EPI == 2) {
                float s = vv + bias[c];
                out0[(size_t)r * ldo + (c - colbase)] =
                    fmaxf(s, 0.f) + log1pf(expf(-fabsf(s)));
            } else {
                out0[(size_t)r * ldo + (c - colbase)] = vv;
            }
        }
    }
}

// ---------------------------------------------------------------------------
// Small GEMM for x_proj (32 cols), 256 threads (round-5 structure).
// ---------------------------------------------------------------------------
__global__ __launch_bounds__(256) void gemm_nt32(
    const float* A, const float* W, float* out0, int K, int ldo)
{
    __shared__ float As[16][65];
    __shared__ float Ws[16][33];
    const int tid = threadIdx.x;
    const int row0 = blockIdx.x * 64;
    const int tr = (tid / 16) * 4;
    const int tc = (tid % 16) * 2;
    float acc[4][2];
#pragma unroll
    for (int i = 0; i < 4; i++) { acc[i][0] = 0.f; acc[i][1] = 0.f; }
    for (int k0 = 0; k0 < K; k0 += 16) {
        __syncthreads();
        for (int i = tid; i < 64 * 16; i += 256) {
            int m = i / 16, k = i % 16;
            As[k][m] = A[(size_t)(row0 + m) * K + k0 + k];
        }
        for (int i = tid; i < 32 * 16; i += 256) {
            int n = i / 16, k = i % 16;
            Ws[k][n] = W[(size_t)n * K + k0 + k];
        }
        __syncthreads();
#pragma unroll
        for (int kk = 0; kk < 16; kk++) {
            float a[4], b[2];
#pragma unroll
            for (int i = 0; i < 4; i++) a[i] = As[kk][tr + i];
            b[0] = Ws[kk][tc]; b[1] = Ws[kk][tc + 1];
#pragma unroll
            for (int i = 0; i < 4; i++) { acc[i][0] += a[i] * b[0]; acc[i][1] += a[i] * b[1]; }
        }
    }
#pragma unroll
    for (int i = 0; i < 4; i++) {
        int r = row0 + tr + i;
        out0[(size_t)r * ldo + tc] = acc[i][0];
        out0[(size_t)r * ldo + tc + 1] = acc[i][1];
    }
}

// ---------------------------------------------------------------------------
// Selective scan (per 128-channel quarter), 3-pass chunked. (round-5, passed)
// ---------------------------------------------------------------------------
__global__ __launch_bounds__(128) void scan_pass1(
    const float* delta_q, const float* u_full, const float* xdbl,
    const float* A_log, int dbase, float* h_end, float* Ssum)
{
    int c = blockIdx.x;
    int dl = threadIdx.x;
    int d = dbase + dl;
    float As[16];
#pragma unroll
    for (int s = 0; s < 16; s++) As[s] = -expf(A_log[d * 16 + s]);
    float h[16];
#pragma unroll
    for (int s = 0; s < 16; s++) h[s] = 0.f;
    float S = 0.f;
    __shared__ float Bs[CHUNK][17];
    int tbase = c * CHUNK;
    for (int i = dl; i < CHUNK * 16; i += 128) {
        int r = i >> 4, s = i & 15;
        Bs[r][s] = xdbl[(size_t)(tbase + r) * 32 + s];
    }
    __syncthreads();
    for (int tl = 0; tl < CHUNK; tl++) {
        size_t t = (size_t)tbase + tl;
        float de = delta_q[t * QCH + dl];
        float uu = u_full[t * DI + d];
        float du = de * uu;
        S += de;
#pragma unroll
        for (int s = 0; s < 16; s++)
            h[s] = __expf(de * As[s]) * h[s] + du * Bs[tl][s];
    }
    size_t base = ((size_t)c * QCH + dl) * 16;
#pragma unroll
    for (int s = 0; s < 16; s++) h_end[base + s] = h[s];
    Ssum[(size_t)c * QCH + dl] = S;
}

__global__ void scan_pass2(const float* h_end, const float* Ssum,
                           const float* A_log, int dbase, float* initS)
{
    int idx = blockIdx.x * blockDim.x + threadIdx.x;   // 0..2047 = dl*16+s
    int dl = idx >> 4;
    float As = -expf(A_log[(dbase + dl) * 16 + (idx & 15)]);
    float carry = 0.f;
    for (int c = 0; c < NCHUNK; c++) {
        initS[(size_t)c * (QCH * 16) + idx] = carry;
        float P = __expf(As * Ssum[(size_t)c * QCH + dl]);
        carry = P * carry + h_end[(size_t)c * (QCH * 16) + idx];
    }
}

__global__ __launch_bounds__(128) void scan_pass3(
    const float* delta_q, const float* u_full, const float* xdbl,
    const float* A_log, int dbase, const float* initS, const float* Dp,
    float* wg_ymod)
{
    int c = blockIdx.x;
    int dl = threadIdx.x;
    int d = dbase + dl;
    float As[16];
#pragma unroll
    for (int s = 0; s < 16; s++) As[s] = -expf(A_log[d * 16 + s]);
    float h[16];
#pragma unroll
    for (int s = 0; s < 16; s++)
        h[s] = initS[((size_t)c * QCH + dl) * 16 + s];
    float Dd = Dp[d];
    __shared__ float Bs[CHUNK][17];
    __shared__ float Cs[CHUNK][17];
    int tbase = c * CHUNK;
    for (int i = dl; i < CHUNK * 16; i += 128) {
        int r = i >> 4, s = i & 15;
        Bs[r][s] = xdbl[(size_t)(tbase + r) * 32 + s];
        Cs[r][s] = xdbl[(size_t)(tbase + r) * 32 + 16 + s];
    }
    __syncthreads();
    for (int tl = 0; tl < CHUNK; tl++) {
        size_t t = (size_t)tbase + tl;
        float de = delta_q[t * QCH + dl];
        float uu = u_full[t * DI + d];
        float du = de * uu;
        float y = Dd * uu;
#pragma unroll
        for (int s = 0; s < 16; s++) {
            h[s] = __expf(de * As[s]) * h[s] + du * Bs[tl][s];
            y += h[s] * Cs[tl][s];
        }
        wg_ymod[t * DI + d] = y * wg_ymod[t * DI + d];   // y * w_gate, in place
    }
}

// ---------------------------------------------------------------------------
extern "C" void kernel_launch(void* const* d_in, const int* in_sizes, int n_in,
                              void* d_out, int out_size, void* d_ws, size_t ws_size,
                              hipStream_t stream)
{
    const float* x         = (const float*)d_in[0];
    const float* guidance  = (const float*)d_in[1];
    const float* in_proj_w = (const float*)d_in[2];
    const float* conv_w    = (const float*)d_in[3];
    const float* conv_b    = (const float*)d_in[4];
    const float* x_proj_w  = (const float*)d_in[5];
    const float* dt_proj_w = (const float*)d_in[6];
    const float* dt_proj_b = (const float*)d_in[7];
    const float* gg1_w     = (const float*)d_in[8];
    const float* gg1_b     = (const float*)d_in[9];
    const float* ln_g      = (const float*)d_in[10];
    const float* ln_b      = (const float*)d_in[11];
    const float* gg2_w     = (const float*)d_in[12];
    const float* gg2_b     = (const float*)d_in[13];
    const float* A_log     = (const float*)d_in[14];
    const float* Dp        = (const float*)d_in[15];
    const float* out_proj_w= (const float*)d_in[16];
    float* out = (float*)d_out;

    // ws: two N x 512 fp32 buffers = 256 MiB exactly.
    float* P1 = (float*)d_ws;                    // x_mod (scan u)
    float* P2 = P1 + (size_t)NTOK * DI;          // w_gate -> y_mod (in place)

    // d_out as pre-final scratch (48.25 MiB used + 2 MiB Wg of 64;
    // final GEMM overwrites all).
    float* ob      = (float*)d_out;
    float* delta_q = ob;                                  // N x 128   (32 MiB)
    float* xdbl    = ob + (size_t)NTOK * QCH;             // N x 32    (8 MiB)
    float* h_end   = ob + (size_t)NTOK * (QCH + 32);      // 4 MiB
    float* Ssum    = h_end + (size_t)NCHUNK * QCH * DS;   // 0.25 MiB
    float* initS   = Ssum + (size_t)NCHUNK * QCH;         // 4 MiB
    // bf16 hi/lo split of gg2_w's two used 512x512 blocks (2 MiB), in the
    // free tail of d_out (floats 12,648,448 .. 13,697,024 of 16,777,216).
    unsigned short* Wg = (unsigned short*)(initS + (size_t)NCHUNK * QCH * DS);

    // 0. W split-precision prep (independent of everything else)
    wprep_kernel<<<512, 256, 0, stream>>>(gg2_w, Wg);
    // 1. in_proj + conv + silu -> P1 = silu(conv(x_in)), P2 = silu(z)
    in_conv_kernel<<<NTOK / 64, 512, 0, stream>>>(
        x, in_proj_w, conv_w, conv_b, P1, P2);
    // 2. gates (bf16x3 MFMA): P1 *= gate_in, P2 *= gate_out
    gates_mfma_kernel<<<dim3(NTOK / 64, 2), 512, 0, stream>>>(
        guidance, gg1_w, gg1_b, ln_g, ln_b, Wg, gg2_b, P1, P2);
    // 3. xdbl = x_mod @ x_proj_w.T  (B|C)
    gemm_nt32<<<NTOK / 64, 256, 0, stream>>>(P1, x_proj_w, xdbl, DI, 32);
    // 4. per 128-channel quarter: delta GEMM + 3-pass scan (y_mod over P2)
    for (int q = 0; q < 4; q++) {
        int dbase = q * QCH;
        gemm512<2><<<dim3(NTOK / 64, 1), 512, 0, stream>>>(
            P1, dt_proj_w, dt_proj_b, delta_q, DI, QCH, dbase);
        scan_pass1<<<NCHUNK, 128, 0, stream>>>(
            delta_q, P1, xdbl, A_log, dbase, h_end, Ssum);
        scan_pass2<<<(QCH * DS) / 256, 256, 0, stream>>>(
            h_end, Ssum, A_log, dbase, initS);
        scan_pass3<<<NCHUNK, 128, 0, stream>>>(
            delta_q, P1, xdbl, A_log, dbase, initS, Dp, P2);
    }
    // 5. out = y_mod @ out_proj_w.T  (overwrites all d_out scratch)
    gemm512<0><<<dim3(NTOK / 64, 2), 512, 0, stream>>>(
        P2, out_proj_w, nullptr, out, DI, DMODEL, 0);
}

// Round 2
// 3601.781 us; speedup vs baseline: 1.2497x; 1.1942x over previous
//
#include <hip/hip_runtime.h>
#include <math.h>

#define NTOK 65536
#define DMODEL 256
#define DI 512
#define DS 16
#define CHUNK 128
#define NCHUNK (NTOK / CHUNK)   // 512
#define QCH 128                 // channels per scan quarter

typedef __bf16 bf16x8 __attribute__((ext_vector_type(8)));
typedef float  f32x4  __attribute__((ext_vector_type(4)));

__device__ __forceinline__ float sigf(float x) { return 1.0f / (1.0f + expf(-x)); }

// ---------------------------------------------------------------------------
// in_conv_kernel: unchanged (round-5 verified)
// ---------------------------------------------------------------------------
__global__ __launch_bounds__(512) void in_conv_kernel(
    const float* x, const float* in_proj_w, const float* conv_w,
    const float* conv_b, float* P1, float* P2)
{
    __shared__ float As[32][72];    // [k][row: 0..3 halo, 4..67 main]
    __shared__ float Wt[32][132];
    __shared__ float xt[68][132];
    const int tid = threadIdx.x;
    const int row0 = blockIdx.x * 64;
    const int tr = (tid & 15) * 4;
    const int tc = (tid >> 4) * 4;
    const int hr = tid >> 7;        // 0..3
    const int hc = tid & 127;       // 0..127

    for (int ct = 0; ct < 8; ct++) {
        float acc[4][4];
#pragma unroll
        for (int i = 0; i < 4; i++)
#pragma unroll
            for (int j = 0; j < 4; j++) acc[i][j] = 0.f;
        float acch = 0.f;
        for (int k0 = 0; k0 < 256; k0 += 32) {
            __syncthreads();
            for (int i = tid; i < 68 * 32; i += 512) {
                int l = i >> 5, k = i & 31;
                int gr = row0 - 4 + l;
                As[k][l] = (gr >= 0) ? x[(size_t)gr * 256 + k0 + k] : 0.f;
            }
            {
                int n = tid >> 2, kq = (tid & 3) * 8;
                const float* wp = in_proj_w + (size_t)(ct * 128 + n) * 256 + k0 + kq;
                float4 w0 = *(const float4*)wp, w1 = *(const float4*)(wp + 4);
                Wt[kq + 0][n] = w0.x; Wt[kq + 1][n] = w0.y;
                Wt[kq + 2][n] = w0.z; Wt[kq + 3][n] = w0.w;
                Wt[kq + 4][n] = w1.x; Wt[kq + 5][n] = w1.y;
                Wt[kq + 6][n] = w1.z; Wt[kq + 7][n] = w1.w;
            }
            __syncthreads();
#pragma unroll 8
            for (int kk = 0; kk < 32; kk++) {
                float4 a = *(const float4*)&As[kk][4 + tr];
                float4 b = *(const float4*)&Wt[kk][tc];
                acc[0][0] += a.x*b.x; acc[0][1] += a.x*b.y; acc[0][2] += a.x*b.z; acc[0][3] += a.x*b.w;
                acc[1][0] += a.y*b.x; acc[1][1] += a.y*b.y; acc[1][2] += a.y*b.z; acc[1][3] += a.y*b.w;
                acc[2][0] += a.z*b.x; acc[2][1] += a.z*b.y; acc[2][2] += a.z*b.z; acc[2][3] += a.z*b.w;
                acc[3][0] += a.w*b.x; acc[3][1] += a.w*b.y; acc[3][2] += a.w*b.z; acc[3][3] += a.w*b.w;
                if (ct < 4) acch += As[kk][hr] * Wt[kk][hc];
            }
        }
        if (ct < 4) {
            __syncthreads();
#pragma unroll
            for (int i = 0; i < 4; i++)
#pragma unroll
                for (int j = 0; j < 4; j++)
                    xt[4 + tr + i][tc + j] = acc[i][j];
            xt[hr][hc] = acch;
            __syncthreads();
#pragma unroll
            for (int i = 0; i < 4; i++) {
                int r = row0 + tr + i;
#pragma unroll
                for (int j = 0; j < 4; j++) {
                    int c = ct * 128 + tc + j;
                    float cv = conv_b[c];
#pragma unroll
                    for (int k = 0; k < 4; k++)
                        cv += conv_w[c * 4 + k] * xt[tr + i + 1 + k][tc + j];
                    P1[(size_t)r * 512 + c] = cv * sigf(cv);
                }
            }
        } else {
#pragma unroll
            for (int i = 0; i < 4; i++) {
                int r = row0 + tr + i;
                float4 zv;
                zv.x = acc[i][0]; zv.y = acc[i][1]; zv.z = acc[i][2]; zv.w = acc[i][3];
                zv.x = zv.x * sigf(zv.x); zv.y = zv.y * sigf(zv.y);
                zv.z = zv.z * sigf(zv.z); zv.w = zv.w * sigf(zv.w);
                *(float4*)&P2[(size_t)r * 512 + (ct - 4) * 128 + tc] = zv;
            }
        }
    }
}

// ---------------------------------------------------------------------------
// wprep_kernel: split the two used 512x512 blocks of gg2_w into hi/lo bf16,
// in per-wave-fragment packet order for DIRECT global->register loads:
//   packet p = (((gm*16 + kc)*2 + hl)*512 + c)*4 + lg      (16B = 8 bf16)
//   element j of packet = W[gm*1024 + c][kc*32 + lg*8 + j]  (hi or lo part)
// A wave's 64 lanes for one (fn) fragment read 16 cols x 4 lg = 1024B
// contiguous -> perfectly coalesced.
// ---------------------------------------------------------------------------
__global__ __launch_bounds__(256) void wprep_kernel(
    const float* gg2_w, unsigned short* Wg)
{
    int p = blockIdx.x * 256 + threadIdx.x;   // 0 .. 131071
    int lg = p & 3;
    int c  = (p >> 2) & 511;
    int hl = (p >> 11) & 1;
    int kc = (p >> 12) & 15;
    int gm = p >> 16;
    int row = gm * 1024 + c;                  // gate_in rows 0..511, gate_out 1024..1535
    const float* src = gg2_w + (size_t)row * 512 + kc * 32 + lg * 8;
    union { unsigned short u[8]; float4 f; } outv;
#pragma unroll
    for (int j = 0; j < 8; j++) {
        float x = src[j];
        __bf16 h = (__bf16)x;
        union { __bf16 b; unsigned short us; } cv;
        if (hl) cv.b = (__bf16)(x - (float)h); else cv.b = h;
        outv.u[j] = cv.us;
    }
    *(float4*)(Wg + (size_t)p * 8) = outv.f;
}

// ---------------------------------------------------------------------------
// gates_mfma_kernel v2: barrier-free streaming MFMA.
//   Phase A: g = gelu(LN(guidance @ gg1_w.T + gg1_b)); thread (tok,o) owns
//     8 consecutive-dim octets d = m*64 + o*8 + {0..7}; stages hi/lo bf16
//     into LDS ONCE (XOR-swizzled 16B packets, conflict-free), one barrier.
//   Phase B: NO barriers. 8 waves; wave wn owns 64 tokens x 64 cols.
//     Per 32-k chunk: 8 ds_read_b128 (A frags) + 8 coalesced global 16B
//     loads (W frags, register double-buffered) + 48 MFMAs:
//     acc = Ah*Wh + Ah*Wl + Al*Wh  (fp32 accumulate).
// grid: (NTOK/64) x 1; LDS 132.5 KiB -> 1 block/CU, 2 waves/SIMD.
// ---------------------------------------------------------------------------
__global__ __launch_bounds__(512, 2) void gates_mfma_kernel(
    const float* guidance, const float* gg1_w, const float* gg1_b,
    const float* ln_g, const float* ln_b,
    const unsigned short* Wg, const float* gg2_b,
    float* P1, float* P2)
{
    __shared__ unsigned short AhL[64 * 512];   // 64 KiB  [tok][k] swizzled
    __shared__ unsigned short AlL[64 * 512];   // 64 KiB
    __shared__ float red_s[64][9], red_q[64][9];

    const int tid = threadIdx.x;
    const int tok = tid & 63;
    const int o   = tid >> 6;        // 0..7 == wave id
    const int row0 = blockIdx.x * 64;

    // ---- Phase A: g (LN + gelu), octet-major dim ownership ----
    float g0 = guidance[(size_t)(row0 + tok) * 3 + 0];
    float g1 = guidance[(size_t)(row0 + tok) * 3 + 1];
    float g2 = guidance[(size_t)(row0 + tok) * 3 + 2];
    float v[64];
    float sum = 0.f, sumsq = 0.f;
#pragma unroll
    for (int m = 0; m < 8; m++)
#pragma unroll
        for (int jj = 0; jj < 8; jj++) {
            int d = m * 64 + o * 8 + jj;
            float t = gg1_w[d * 3 + 0] * g0 + gg1_w[d * 3 + 1] * g1 +
                      gg1_w[d * 3 + 2] * g2 + gg1_b[d];
            v[m * 8 + jj] = t;
            sum += t; sumsq += t * t;
        }
    red_s[tok][o] = sum; red_q[tok][o] = sumsq;
    __syncthreads();
    sum = 0.f; sumsq = 0.f;
#pragma unroll
    for (int oo = 0; oo < 8; oo++) { sum += red_s[tok][oo]; sumsq += red_q[tok][oo]; }
    float mu = sum * (1.f / 512.f);
    float var = fmaxf(sumsq * (1.f / 512.f) - mu * mu, 0.f);
    float rstd = 1.f / sqrtf(var + 1e-5f);
    // gelu + hi/lo split + one 16B packet write per octet (min bank traffic)
#pragma unroll
    for (int m = 0; m < 8; m++) {
        bf16x8 hoct, loct;
#pragma unroll
        for (int jj = 0; jj < 8; jj++) {
            int d = m * 64 + o * 8 + jj;
            float t = (v[m * 8 + jj] - mu) * rstd * ln_g[d] + ln_b[d];
            t = 0.5f * t * (1.f + erff(t * 0.70710678118654752440f));
            __bf16 h = (__bf16)t;
            hoct[jj] = h;
            loct[jj] = (__bf16)(t - (float)h);
        }
        // octet k8 = m*8 + o ; packet = (tok*64 + k8) ^ (tok&7)
        int pidx = ((tok * 64 + (m * 8 + o)) ^ (tok & 7)) * 8;
        *(bf16x8*)&AhL[pidx] = hoct;
        *(bf16x8*)&AlL[pidx] = loct;
    }
    __syncthreads();     // the ONLY barrier before Phase B

    // ---- Phase B: barrier-free MFMA streaming ----
    const int l  = tid & 63;
    const int wn = tid >> 6;         // wave col-slice: cols wn*64 .. +63
    const int lr = l & 15;
    const int lg = l >> 4;

    for (int gm = 0; gm < 2; gm++) {
        f32x4 acc[4][4];
#pragma unroll
        for (int fm = 0; fm < 4; fm++)
#pragma unroll
            for (int fn = 0; fn < 4; fn++)
                acc[fm][fn] = (f32x4){0.f, 0.f, 0.f, 0.f};

        bf16x8 whA[4], wlA[4], whB[4], wlB[4];

        auto loadW = [&](int kc, bf16x8 (&wh)[4], bf16x8 (&wl)[4]) {
            const unsigned short* bh = Wg + (size_t)(((gm * 16 + kc) * 2 + 0) * 2048) * 8;
            const unsigned short* bl = Wg + (size_t)(((gm * 16 + kc) * 2 + 1) * 2048) * 8;
            int pk = (wn * 64 + lr) * 4 + lg;
#pragma unroll
            for (int fn = 0; fn < 4; fn++) {
                wh[fn] = *(const bf16x8*)(bh + (size_t)(pk + fn * 64) * 8);
                wl[fn] = *(const bf16x8*)(bl + (size_t)(pk + fn * 64) * 8);
            }
        };
        auto doChunk = [&](int kc, const bf16x8 (&wh)[4], const bf16x8 (&wl)[4]) {
#pragma unroll
            for (int fm = 0; fm < 4; fm++) {
                int t = fm * 16 + lr;
                int pidx = ((t * 64 + kc * 4 + lg) ^ (lr & 7)) * 8;
                bf16x8 ah = *(const bf16x8*)&AhL[pidx];
                bf16x8 al = *(const bf16x8*)&AlL[pidx];
#pragma unroll
                for (int fn = 0; fn < 4; fn++) {
                    acc[fm][fn] = __builtin_amdgcn_mfma_f32_16x16x32_bf16(
                        ah, wh[fn], acc[fm][fn], 0, 0, 0);
                    acc[fm][fn] = __builtin_amdgcn_mfma_f32_16x16x32_bf16(
                        ah, wl[fn], acc[fm][fn], 0, 0, 0);
                    acc[fm][fn] = __builtin_amdgcn_mfma_f32_16x16x32_bf16(
                        al, wh[fn], acc[fm][fn], 0, 0, 0);
                }
            }
        };

        loadW(0, whA, wlA);
        for (int kc = 0; kc < 16; kc += 2) {
            loadW(kc + 1, whB, wlB);
            doChunk(kc, whA, wlA);
            if (kc + 2 < 16) loadW(kc + 2, whA, wlA);
            doChunk(kc + 1, whB, wlB);
        }

        // Epilogue: C/D layout col = lane&15, row = (lane>>4)*4 + reg (m89).
        float* P = gm ? P2 : P1;
        const float* bias = gg2_b + gm * 1024;
#pragma unroll
        for (int fm = 0; fm < 4; fm++)
#pragma unroll
            for (int fn = 0; fn < 4; fn++) {
                int col = wn * 64 + fn * 16 + lr;
                float b = bias[col];
#pragma unroll
                for (int q = 0; q < 4; q++) {
                    int r = row0 + fm * 16 + lg * 4 + q;
                    size_t idx = (size_t)r * 512 + col;
                    P[idx] *= sigf(acc[fm][fn][q] + b);
                }
            }
    }
}

// ---------------------------------------------------------------------------
// gemm512: out = A(N,K) @ W(M,K).T, 64x128 tile, 512 threads, float4 reads.
// EPI 0: plain store   EPI 2: softplus(v + bias[c])
// ---------------------------------------------------------------------------
template <int EPI>
__global__ __launch_bounds__(512) void gemm512(
    const float* A, const float* W, const float* bias,
    float* out0, int K, int ldo, int colbase)
{
    __shared__ float As[32][68];
    __shared__ float Wt[32][132];
    const int tid = threadIdx.x;
    const int row0 = blockIdx.x * 64;
    const int col0 = colbase + blockIdx.y * 128;
    const int tr = (tid & 15) * 4;
    const int tc = (tid >> 4) * 4;
    float acc[4][4];
#pragma unroll
    for (int i = 0; i < 4; i++)
#pragma unroll
        for (int j = 0; j < 4; j++) acc[i][j] = 0.f;

    for (int k0 = 0; k0 < K; k0 += 32) {
        __syncthreads();
        for (int i = tid; i < 64 * 32; i += 512) {
            int l = i >> 5, k = i & 31;
            As[k][l] = A[(size_t)(row0 + l) * K + k0 + k];
        }
        {
            int n = tid >> 2, kq = (tid & 3) * 8;
            const float* wp = W + (size_t)(col0 + n) * K + k0 + kq;
            float4 w0 = *(const float4*)wp, w1 = *(const float4*)(wp + 4);
            Wt[kq + 0][n] = w0.x; Wt[kq + 1][n] = w0.y;
            Wt[kq + 2][n] = w0.z; Wt[kq + 3][n] = w0.w;
            Wt[kq + 4][n] = w1.x; Wt[kq + 5][n] = w1.y;
            Wt[kq + 6][n] = w1.z; Wt[kq + 7][n] = w1.w;
        }
        __syncthreads();
#pragma unroll 8
        for (int kk = 0; kk < 32; kk++) {
            float4 a = *(const float4*)&As[kk][tr];
            float4 b = *(const float4*)&Wt[kk][tc];
            acc[0][0] += a.x*b.x; acc[0][1] += a.x*b.y; acc[0][2] += a.x*b.z; acc[0][3] += a.x*b.w;
            acc[1][0] += a.y*b.x; acc[1][1] += a.y*b.y; acc[1][2] += a.y*b.z; acc[1][3] += a.y*b.w;
            acc[2][0] += a.z*b.x; acc[2][1] += a.z*b.y; acc[2][2] += a.z*b.z; acc[2][3] += a.z*b.w;
            acc[3][0] += a.w*b.x; acc[3][1] += a.w*b.y; acc[3][2] += a.w*b.z; acc[3][3] += a.w*b.w;
        }
    }
#pragma unroll
    for (int i = 0; i < 4; i++) {
        int r = row0 + tr + i;
#pragma unroll
        for (int j = 0; j < 4; j++) {
            int c = col0 + tc + j;
            float vv = acc[i][j];
            if (EPI == 2) {
                float s = vv + bias[c];
                out0[(size_t)r * ldo + (c - colbase)] =
                    fmaxf(s, 0.f) + log1pf(expf(-fabsf(s)));
            } else {
                out0[(size_t)r * ldo + (c - colbase)] = vv;
            }
        }
    }
}

// ---------------------------------------------------------------------------
// Small GEMM for x_proj (32 cols), 256 threads (round-5 structure).
// ---------------------------------------------------------------------------
__global__ __launch_bounds__(256) void gemm_nt32(
    const float* A, const float* W, float* out0, int K, int ldo)
{
    __shared__ float As[16][65];
    __shared__ float Ws[16][33];
    const int tid = threadIdx.x;
    const int row0 = blockIdx.x * 64;
    const int tr = (tid / 16) * 4;
    const int tc = (tid % 16) * 2;
    float acc[4][2];
#pragma unroll
    for (int i = 0; i < 4; i++) { acc[i][0] = 0.f; acc[i][1] = 0.f; }
    for (int k0 = 0; k0 < K; k0 += 16) {
        __syncthreads();
        for (int i = tid; i < 64 * 16; i += 256) {
            int m = i / 16, k = i % 16;
            As[k][m] = A[(size_t)(row0 + m) * K + k0 + k];
        }
        for (int i = tid; i < 32 * 16; i += 256) {
            int n = i / 16, k = i % 16;
            Ws[k][n] = W[(size_t)n * K + k0 + k];
        }
        __syncthreads();
#pragma unroll
        for (int kk = 0; kk < 16; kk++) {
            float a[4], b[2];
#pragma unroll
            for (int i = 0; i < 4; i++) a[i] = As[kk][tr + i];
            b[0] = Ws[kk][tc]; b[1] = Ws[kk][tc + 1];
#pragma unroll
            for (int i = 0; i < 4; i++) { acc[i][0] += a[i] * b[0]; acc[i][1] += a[i] * b[1]; }
        }
    }
#pragma unroll
    for (int i = 0; i < 4; i++) {
        int r = row0 + tr + i;
        out0[(size_t)r * ldo + tc] = acc[i][0];
        out0[(size_t)r * ldo + tc + 1] = acc[i][1];
    }
}

// ---------------------------------------------------------------------------
// Selective scan (per 128-channel quarter), 3-pass chunked. (round-5, passed)
// ---------------------------------------------------------------------------
__global__ __launch_bounds__(128) void scan_pass1(
    const float* delta_q, const float* u_full, const float* xdbl,
    const float* A_log, int dbase, float* h_end, float* Ssum)
{
    int c = blockIdx.x;
    int dl = threadIdx.x;
    int d = dbase + dl;
    float As[16];
#pragma unroll
    for (int s = 0; s < 16; s++) As[s] = -expf(A_log[d * 16 + s]);
    float h[16];
#pragma unroll
    for (int s = 0; s < 16; s++) h[s] = 0.f;
    float S = 0.f;
    __shared__ float Bs[CHUNK][17];
    int tbase = c * CHUNK;
    for (int i = dl; i < CHUNK * 16; i += 128) {
        int r = i >> 4, s = i & 15;
        Bs[r][s] = xdbl[(size_t)(tbase + r) * 32 + s];
    }
    __syncthreads();
    for (int tl = 0; tl < CHUNK; tl++) {
        size_t t = (size_t)tbase + tl;
        float de = delta_q[t * QCH + dl];
        float uu = u_full[t * DI + d];
        float du = de * uu;
        S += de;
#pragma unroll
        for (int s = 0; s < 16; s++)
            h[s] = __expf(de * As[s]) * h[s] + du * Bs[tl][s];
    }
    size_t base = ((size_t)c * QCH + dl) * 16;
#pragma unroll
    for (int s = 0; s < 16; s++) h_end[base + s] = h[s];
    Ssum[(size_t)c * QCH + dl] = S;
}

__global__ void scan_pass2(const float* h_end, const float* Ssum,
                           const float* A_log, int dbase, float* initS)
{
    int idx = blockIdx.x * blockDim.x + threadIdx.x;   // 0..2047 = dl*16+s
    int dl = idx >> 4;
    float As = -expf(A_log[(dbase + dl) * 16 + (idx & 15)]);
    float carry = 0.f;
    for (int c = 0; c < NCHUNK; c++) {
        initS[(size_t)c * (QCH * 16) + idx] = carry;
        float P = __expf(As * Ssum[(size_t)c * QCH + dl]);
        carry = P * carry + h_end[(size_t)c * (QCH * 16) + idx];
    }
}

__global__ __launch_bounds__(128) void scan_pass3(
    const float* delta_q, const float* u_full, const float* xdbl,
    const float* A_log, int dbase, const float* initS, const float* Dp,
    float* wg_ymod)
{
    int c = blockIdx.x;
    int dl = threadIdx.x;
    int d = dbase + dl;
    float As[16];
#pragma unroll
    for (int s = 0; s < 16; s++) As[s] = -expf(A_log[d * 16 + s]);
    float h[16];
#pragma unroll
    for (int s = 0; s < 16; s++)
        h[s] = initS[((size_t)c * QCH + dl) * 16 + s];
    float Dd = Dp[d];
    __shared__ float Bs[CHUNK][17];
    __shared__ float Cs[CHUNK][17];
    int tbase = c * CHUNK;
    for (int i = dl; i < CHUNK * 16; i += 128) {
        int r = i >> 4, s = i & 15;
        Bs[r][s] = xdbl[(size_t)(tbase + r) * 32 + s];
        Cs[r][s] = xdbl[(size_t)(tbase + r) * 32 + 16 + s];
    }
    __syncthreads();
    for (int tl = 0; tl < CHUNK; tl++) {
        size_t t = (size_t)tbase + tl;
        float de = delta_q[t * QCH + dl];
        float uu = u_full[t * DI + d];
        float du = de * uu;
        float y = Dd * uu;
#pragma unroll
        for (int s = 0; s < 16; s++) {
            h[s] = __expf(de * As[s]) * h[s] + du * Bs[tl][s];
            y += h[s] * Cs[tl][s];
        }
        wg_ymod[t * DI + d] = y * wg_ymod[t * DI + d];   // y * w_gate, in place
    }
}

// ---------------------------------------------------------------------------
extern "C" void kernel_launch(void* const* d_in, const int* in_sizes, int n_in,
                              void* d_out, int out_size, void* d_ws, size_t ws_size,
                              hipStream_t stream)
{
    const float* x         = (const float*)d_in[0];
    const float* guidance  = (const float*)d_in[1];
    const float* in_proj_w = (const float*)d_in[2];
    const float* conv_w    = (const float*)d_in[3];
    const float* conv_b    = (const float*)d_in[4];
    const float* x_proj_w  = (const float*)d_in[5];
    const float* dt_proj_w = (const float*)d_in[6];
    const float* dt_proj_b = (const float*)d_in[7];
    const float* gg1_w     = (const float*)d_in[8];
    const float* gg1_b     = (const float*)d_in[9];
    const float* ln_g      = (const float*)d_in[10];
    const float* ln_b      = (const float*)d_in[11];
    const float* gg2_w     = (const float*)d_in[12];
    const float* gg2_b     = (const float*)d_in[13];
    const float* A_log     = (const float*)d_in[14];
    const float* Dp        = (const float*)d_in[15];
    const float* out_proj_w= (const float*)d_in[16];
    float* out = (float*)d_out;

    // ws: two N x 512 fp32 buffers = 256 MiB exactly.
    float* P1 = (float*)d_ws;                    // x_mod (scan u)
    float* P2 = P1 + (size_t)NTOK * DI;          // w_gate -> y_mod (in place)

    // d_out as pre-final scratch (48.25 MiB used + 2 MiB Wg of 64;
    // final GEMM overwrites all).
    float* ob      = (float*)d_out;
    float* delta_q = ob;                                  // N x 128   (32 MiB)
    float* xdbl    = ob + (size_t)NTOK * QCH;             // N x 32    (8 MiB)
    float* h_end   = ob + (size_t)NTOK * (QCH + 32);      // 4 MiB
    float* Ssum    = h_end + (size_t)NCHUNK * QCH * DS;   // 0.25 MiB
    float* initS   = Ssum + (size_t)NCHUNK * QCH;         // 4 MiB
    // bf16 hi/lo split of gg2_w's two used 512x512 blocks (2 MiB), in the
    // free tail of d_out (floats 12,648,448 .. 13,697,024 of 16,777,216).
    unsigned short* Wg = (unsigned short*)(initS + (size_t)NCHUNK * QCH * DS);

    // 0. W split-precision prep (independent of everything else)
    wprep_kernel<<<512, 256, 0, stream>>>(gg2_w, Wg);
    // 1. in_proj + conv + silu -> P1 = silu(conv(x_in)), P2 = silu(z)
    in_conv_kernel<<<NTOK / 64, 512, 0, stream>>>(
        x, in_proj_w, conv_w, conv_b, P1, P2);
    // 2. gates (barrier-free bf16x3 MFMA): P1 *= gate_in, P2 *= gate_out
    gates_mfma_kernel<<<NTOK / 64, 512, 0, stream>>>(
        guidance, gg1_w, gg1_b, ln_g, ln_b, Wg, gg2_b, P1, P2);
    // 3. xdbl = x_mod @ x_proj_w.T  (B|C)
    gemm_nt32<<<NTOK / 64, 256, 0, stream>>>(P1, x_proj_w, xdbl, DI, 32);
    // 4. per 128-channel quarter: delta GEMM + 3-pass scan (y_mod over P2)
    for (int q = 0; q < 4; q++) {
        int dbase = q * QCH;
        gemm512<2><<<dim3(NTOK / 64, 1), 512, 0, stream>>>(
            P1, dt_proj_w, dt_proj_b, delta_q, DI, QCH, dbase);
        scan_pass1<<<NCHUNK, 128, 0, stream>>>(
            delta_q, P1, xdbl, A_log, dbase, h_end, Ssum);
        scan_pass2<<<(QCH * DS) / 256, 256, 0, stream>>>(
            h_end, Ssum, A_log, dbase, initS);
        scan_pass3<<<NCHUNK, 128, 0, stream>>>(
            delta_q, P1, xdbl, A_log, dbase, initS, Dp, P2);
    }
    // 5. out = y_mod @ out_proj_w.T  (overwrites all d_out scratch)
    gemm512<0><<<dim3(NTOK / 64, 2), 512, 0, stream>>>(
        P2, out_proj_w, nullptr, out, DI, DMODEL, 0);
}

// Round 3
// 2990.484 us; speedup vs baseline: 1.5051x; 1.2044x over previous
//
#include <hip/hip_runtime.h>
#include <math.h>

#define NTOK 65536
#define DMODEL 256
#define DI 512
#define DS 16
#define CHUNK 128
#define NCHUNK (NTOK / CHUNK)   // 512
#define QCH 128                 // channels per scan quarter

typedef __bf16 bf16x8 __attribute__((ext_vector_type(8)));
typedef float  f32x4  __attribute__((ext_vector_type(4)));

__device__ __forceinline__ float sigf(float x) { return 1.0f / (1.0f + expf(-x)); }

// ---------------------------------------------------------------------------
// wprep_kernel: split the two used 512x512 blocks of gg2_w into hi/lo bf16,
// in per-wave-fragment packet order for DIRECT global->register loads:
//   packet p = (((gm*16 + kc)*2 + hl)*512 + c)*4 + lg      (16B = 8 bf16)
//   element j of packet = W[gm*1024 + c][kc*32 + lg*8 + j]  (hi or lo part)
// ---------------------------------------------------------------------------
__global__ __launch_bounds__(256) void wprep_kernel(
    const float* gg2_w, unsigned short* Wg)
{
    int p = blockIdx.x * 256 + threadIdx.x;   // 0 .. 131071
    int lg = p & 3;
    int c  = (p >> 2) & 511;
    int hl = (p >> 11) & 1;
    int kc = (p >> 12) & 15;
    int gm = p >> 16;
    int row = gm * 1024 + c;                  // gate_in rows 0..511, gate_out 1024..1535
    const float* src = gg2_w + (size_t)row * 512 + kc * 32 + lg * 8;
    union { unsigned short u[8]; float4 f; } outv;
#pragma unroll
    for (int j = 0; j < 8; j++) {
        float x = src[j];
        __bf16 h = (__bf16)x;
        union { __bf16 b; unsigned short us; } cv;
        if (hl) cv.b = (__bf16)(x - (float)h); else cv.b = h;
        outv.u[j] = cv.us;
    }
    *(float4*)(Wg + (size_t)p * 8) = outv.f;
}

// ---------------------------------------------------------------------------
// wprep_inproj: split in_proj_w (1024 x 256) into hi/lo bf16, fragment order:
//   packet p = (((gm*8 + kc)*2 + hl)*512 + c)*4 + lg    (16B = 8 bf16)
//   element j = in_proj_w[gm*512 + c][kc*32 + lg*8 + j]
//   gm=0: x_in half (rows 0..511); gm=1: z half (rows 512..1023). 1 MiB.
// ---------------------------------------------------------------------------
__global__ __launch_bounds__(256) void wprep_inproj(
    const float* in_proj_w, unsigned short* Wg2)
{
    int p = blockIdx.x * 256 + threadIdx.x;   // 0 .. 65535
    int lg = p & 3;
    int c  = (p >> 2) & 511;
    int hl = (p >> 11) & 1;
    int kc = (p >> 12) & 7;
    int gm = p >> 15;
    const float* src = in_proj_w + (size_t)(gm * 512 + c) * 256 + kc * 32 + lg * 8;
    union { unsigned short u[8]; float4 f; } outv;
#pragma unroll
    for (int j = 0; j < 8; j++) {
        float x = src[j];
        __bf16 h = (__bf16)x;
        union { __bf16 b; unsigned short us; } cv;
        if (hl) cv.b = (__bf16)(x - (float)h); else cv.b = h;
        outv.u[j] = cv.us;
    }
    *(float4*)(Wg2 + (size_t)p * 8) = outv.f;
}

// ---------------------------------------------------------------------------
// in_conv_mfma: bf16x3 streaming-MFMA version of in_proj + conv + silu.
//   Phase A: x tile (64 rows + 4 halo + zeros -> 80 x 256) split hi/lo bf16
//     into swizzled LDS packets, one barrier.
//   Phase B (barrier-free): 8 waves, wave wn owns cols wn*64..+63 of each
//     512-col half. W fragments streamed global->reg (double-buffered).
//     z half: 4 fm tiles; x_in half: 5 fm tiles (5th = halo rows 64..79).
//   Epilogue: z = silu directly from acc; x_in staged to per-wave LDS slab
//     (A-LDS repurposed after a barrier), causal conv4 + bias + silu.
// LDS 80 KiB; __launch_bounds__(512,2) caps VGPR at 256.
// ---------------------------------------------------------------------------
#define MFMA_CHUNK(NFM, KC, WH, WL)                                           \
    _Pragma("unroll")                                                         \
    for (int fm = 0; fm < NFM; fm++) {                                        \
        int t = (fm < 4) ? (fm * 16 + lr) : (64 + lr);                        \
        int pidx = (t * 32 + (((KC) * 4 + lg) ^ (t & 7))) * 8;                \
        bf16x8 ah = *(const bf16x8*)&AhL[pidx];                               \
        bf16x8 al = *(const bf16x8*)&AlL[pidx];                               \
        _Pragma("unroll")                                                     \
        for (int fn = 0; fn < 4; fn++) {                                      \
            acc[fm][fn] = __builtin_amdgcn_mfma_f32_16x16x32_bf16(ah, WH[fn], acc[fm][fn], 0, 0, 0); \
            acc[fm][fn] = __builtin_amdgcn_mfma_f32_16x16x32_bf16(ah, WL[fn], acc[fm][fn], 0, 0, 0); \
            acc[fm][fn] = __builtin_amdgcn_mfma_f32_16x16x32_bf16(al, WH[fn], acc[fm][fn], 0, 0, 0); \
        }                                                                     \
    }

__global__ __launch_bounds__(512, 2) void in_conv_mfma(
    const float* x, const unsigned short* Wg2, const float* conv_w,
    const float* conv_b, float* P1, float* P2)
{
    __shared__ __align__(16) unsigned short smem[2 * 80 * 256];  // 80 KiB
    unsigned short* AhL = smem;
    unsigned short* AlL = smem + 80 * 256;
    float* xs = (float*)smem;          // repurposed: [8 waves][68][33] fp32

    const int tid = threadIdx.x;
    const int row0 = blockIdx.x * 64;
    const int l  = tid & 63;
    const int wn = tid >> 6;           // wave id / col-slice
    const int lr = l & 15;
    const int lg = l >> 4;

    // ---- Phase A: stage x split hi/lo (rows 0..63 main, 64..67 halo, rest 0)
    for (int i = tid; i < 80 * 32; i += 512) {
        int t = i >> 5, k8 = i & 31;
        float xv[8];
#pragma unroll
        for (int j = 0; j < 8; j++) xv[j] = 0.f;
        if (t < 68) {
            int gr = (t < 64) ? (row0 + t) : (row0 - 68 + t);
            if (gr >= 0) {
                float4 a0 = *(const float4*)(x + (size_t)gr * 256 + k8 * 8);
                float4 a1 = *(const float4*)(x + (size_t)gr * 256 + k8 * 8 + 4);
                xv[0]=a0.x; xv[1]=a0.y; xv[2]=a0.z; xv[3]=a0.w;
                xv[4]=a1.x; xv[5]=a1.y; xv[6]=a1.z; xv[7]=a1.w;
            }
        }
        bf16x8 ho, lo;
#pragma unroll
        for (int j = 0; j < 8; j++) {
            __bf16 hh = (__bf16)xv[j];
            ho[j] = hh;
            lo[j] = (__bf16)(xv[j] - (float)hh);
        }
        int pidx = (t * 32 + (k8 ^ (t & 7))) * 8;
        *(bf16x8*)&AhL[pidx] = ho;
        *(bf16x8*)&AlL[pidx] = lo;
    }
    __syncthreads();

    auto loadW = [&](int gm, int kc, bf16x8 (&wh)[4], bf16x8 (&wl)[4]) {
        const unsigned short* bh = Wg2 + (size_t)(((gm * 8 + kc) * 2 + 0) * 2048) * 8;
        const unsigned short* bl = Wg2 + (size_t)(((gm * 8 + kc) * 2 + 1) * 2048) * 8;
        const int pk = (wn * 64 + lr) * 4 + lg;
#pragma unroll
        for (int fn = 0; fn < 4; fn++) {
            wh[fn] = *(const bf16x8*)(bh + (size_t)(pk + fn * 64) * 8);
            wl[fn] = *(const bf16x8*)(bl + (size_t)(pk + fn * 64) * 8);
        }
    };

    // ---- z half (gm=1): 4 fm tiles, direct silu epilogue ----
    {
        f32x4 acc[4][4];
#pragma unroll
        for (int fm = 0; fm < 4; fm++)
#pragma unroll
            for (int fn = 0; fn < 4; fn++)
                acc[fm][fn] = (f32x4){0.f, 0.f, 0.f, 0.f};
        bf16x8 whA[4], wlA[4], whB[4], wlB[4];
        loadW(1, 0, whA, wlA);
#pragma unroll
        for (int kc = 0; kc < 8; kc += 2) {
            loadW(1, kc + 1, whB, wlB);
            MFMA_CHUNK(4, kc, whA, wlA)
            if (kc + 2 < 8) loadW(1, kc + 2, whA, wlA);
            MFMA_CHUNK(4, kc + 1, whB, wlB)
        }
#pragma unroll
        for (int fm = 0; fm < 4; fm++)
#pragma unroll
            for (int fn = 0; fn < 4; fn++) {
                int col = wn * 64 + fn * 16 + lr;
#pragma unroll
                for (int q = 0; q < 4; q++) {
                    int r = row0 + fm * 16 + lg * 4 + q;
                    float vz = acc[fm][fn][q];
                    P2[(size_t)r * 512 + col] = vz * sigf(vz);
                }
            }
    }

    // ---- x_in half (gm=0): 5 fm tiles (halo), conv epilogue ----
    {
        f32x4 acc[5][4];
#pragma unroll
        for (int fm = 0; fm < 5; fm++)
#pragma unroll
            for (int fn = 0; fn < 4; fn++)
                acc[fm][fn] = (f32x4){0.f, 0.f, 0.f, 0.f};
        bf16x8 whA[4], wlA[4], whB[4], wlB[4];
        loadW(0, 0, whA, wlA);
#pragma unroll
        for (int kc = 0; kc < 8; kc += 2) {
            loadW(0, kc + 1, whB, wlB);
            MFMA_CHUNK(5, kc, whA, wlA)
            if (kc + 2 < 8) loadW(0, kc + 2, whA, wlA);
            MFMA_CHUNK(5, kc + 1, whB, wlB)
        }

        __syncthreads();                       // all waves done reading A-LDS
        float* xsw = xs + wn * (68 * 33);      // per-wave slab (wave-private)
        const int c_local = l & 31;
        const int rbase = (l >> 5) * 32;
#pragma unroll
        for (int h = 0; h < 2; h++) {
            if (h) __syncthreads();            // uniform; protects slab reuse
            // stage this 32-col half: rows 4..67 = tokens, rows 0..3 = halo
#pragma unroll
            for (int fm = 0; fm < 5; fm++)
#pragma unroll
                for (int ff = 0; ff < 2; ff++) {
                    int fn = h * 2 + ff;
#pragma unroll
                    for (int q = 0; q < 4; q++) {
                        if (fm < 4) {
                            int rr = 4 + fm * 16 + lg * 4 + q;
                            xsw[rr * 33 + ff * 16 + lr] = acc[fm][fn][q];
                        } else if (lg == 0) {
                            xsw[q * 33 + ff * 16 + lr] = acc[fm][fn][q];
                        }
                    }
                }
            asm volatile("s_waitcnt lgkmcnt(0)" ::: "memory");
            int cg = wn * 64 + h * 32 + c_local;
            float w0 = conv_w[cg * 4 + 0], w1 = conv_w[cg * 4 + 1];
            float w2 = conv_w[cg * 4 + 2], w3 = conv_w[cg * 4 + 3];
            float cb = conv_b[cg];
            float s0 = xsw[(rbase + 1) * 33 + c_local];
            float s1 = xsw[(rbase + 2) * 33 + c_local];
            float s2 = xsw[(rbase + 3) * 33 + c_local];
#pragma unroll
            for (int i = 0; i < 32; i++) {
                float s3 = xsw[(rbase + 4 + i) * 33 + c_local];
                float cv = cb + w0 * s0 + w1 * s1 + w2 * s2 + w3 * s3;
                cv = cv * sigf(cv);
                P1[(size_t)(row0 + rbase + i) * 512 + cg] = cv;
                s0 = s1; s1 = s2; s2 = s3;
            }
        }
    }
}

// ---------------------------------------------------------------------------
// gates_mfma_kernel v2: barrier-free streaming MFMA. (round-2 verified)
// ---------------------------------------------------------------------------
__global__ __launch_bounds__(512, 2) void gates_mfma_kernel(
    const float* guidance, const float* gg1_w, const float* gg1_b,
    const float* ln_g, const float* ln_b,
    const unsigned short* Wg, const float* gg2_b,
    float* P1, float* P2)
{
    __shared__ unsigned short AhL[64 * 512];   // 64 KiB  [tok][k] swizzled
    __shared__ unsigned short AlL[64 * 512];   // 64 KiB
    __shared__ float red_s[64][9], red_q[64][9];

    const int tid = threadIdx.x;
    const int tok = tid & 63;
    const int o   = tid >> 6;        // 0..7 == wave id
    const int row0 = blockIdx.x * 64;

    // ---- Phase A: g (LN + gelu), octet-major dim ownership ----
    float g0 = guidance[(size_t)(row0 + tok) * 3 + 0];
    float g1 = guidance[(size_t)(row0 + tok) * 3 + 1];
    float g2 = guidance[(size_t)(row0 + tok) * 3 + 2];
    float v[64];
    float sum = 0.f, sumsq = 0.f;
#pragma unroll
    for (int m = 0; m < 8; m++)
#pragma unroll
        for (int jj = 0; jj < 8; jj++) {
            int d = m * 64 + o * 8 + jj;
            float t = gg1_w[d * 3 + 0] * g0 + gg1_w[d * 3 + 1] * g1 +
                      gg1_w[d * 3 + 2] * g2 + gg1_b[d];
            v[m * 8 + jj] = t;
            sum += t; sumsq += t * t;
        }
    red_s[tok][o] = sum; red_q[tok][o] = sumsq;
    __syncthreads();
    sum = 0.f; sumsq = 0.f;
#pragma unroll
    for (int oo = 0; oo < 8; oo++) { sum += red_s[tok][oo]; sumsq += red_q[tok][oo]; }
    float mu = sum * (1.f / 512.f);
    float var = fmaxf(sumsq * (1.f / 512.f) - mu * mu, 0.f);
    float rstd = 1.f / sqrtf(var + 1e-5f);
#pragma unroll
    for (int m = 0; m < 8; m++) {
        bf16x8 hoct, loct;
#pragma unroll
        for (int jj = 0; jj < 8; jj++) {
            int d = m * 64 + o * 8 + jj;
            float t = (v[m * 8 + jj] - mu) * rstd * ln_g[d] + ln_b[d];
            t = 0.5f * t * (1.f + erff(t * 0.70710678118654752440f));
            __bf16 h = (__bf16)t;
            hoct[jj] = h;
            loct[jj] = (__bf16)(t - (float)h);
        }
        int pidx = ((tok * 64 + (m * 8 + o)) ^ (tok & 7)) * 8;
        *(bf16x8*)&AhL[pidx] = hoct;
        *(bf16x8*)&AlL[pidx] = loct;
    }
    __syncthreads();     // the ONLY barrier before Phase B

    // ---- Phase B: barrier-free MFMA streaming ----
    const int l  = tid & 63;
    const int wn = tid >> 6;
    const int lr = l & 15;
    const int lg = l >> 4;

    for (int gm = 0; gm < 2; gm++) {
        f32x4 acc[4][4];
#pragma unroll
        for (int fm = 0; fm < 4; fm++)
#pragma unroll
            for (int fn = 0; fn < 4; fn++)
                acc[fm][fn] = (f32x4){0.f, 0.f, 0.f, 0.f};

        bf16x8 whA[4], wlA[4], whB[4], wlB[4];

        auto loadW = [&](int kc, bf16x8 (&wh)[4], bf16x8 (&wl)[4]) {
            const unsigned short* bh = Wg + (size_t)(((gm * 16 + kc) * 2 + 0) * 2048) * 8;
            const unsigned short* bl = Wg + (size_t)(((gm * 16 + kc) * 2 + 1) * 2048) * 8;
            int pk = (wn * 64 + lr) * 4 + lg;
#pragma unroll
            for (int fn = 0; fn < 4; fn++) {
                wh[fn] = *(const bf16x8*)(bh + (size_t)(pk + fn * 64) * 8);
                wl[fn] = *(const bf16x8*)(bl + (size_t)(pk + fn * 64) * 8);
            }
        };
        auto doChunk = [&](int kc, const bf16x8 (&wh)[4], const bf16x8 (&wl)[4]) {
#pragma unroll
            for (int fm = 0; fm < 4; fm++) {
                int t = fm * 16 + lr;
                int pidx = ((t * 64 + kc * 4 + lg) ^ (lr & 7)) * 8;
                bf16x8 ah = *(const bf16x8*)&AhL[pidx];
                bf16x8 al = *(const bf16x8*)&AlL[pidx];
#pragma unroll
                for (int fn = 0; fn < 4; fn++) {
                    acc[fm][fn] = __builtin_amdgcn_mfma_f32_16x16x32_bf16(
                        ah, wh[fn], acc[fm][fn], 0, 0, 0);
                    acc[fm][fn] = __builtin_amdgcn_mfma_f32_16x16x32_bf16(
                        ah, wl[fn], acc[fm][fn], 0, 0, 0);
                    acc[fm][fn] = __builtin_amdgcn_mfma_f32_16x16x32_bf16(
                        al, wh[fn], acc[fm][fn], 0, 0, 0);
                }
            }
        };

        loadW(0, whA, wlA);
        for (int kc = 0; kc < 16; kc += 2) {
            loadW(kc + 1, whB, wlB);
            doChunk(kc, whA, wlA);
            if (kc + 2 < 16) loadW(kc + 2, whA, wlA);
            doChunk(kc + 1, whB, wlB);
        }

        float* P = gm ? P2 : P1;
        const float* bias = gg2_b + gm * 1024;
#pragma unroll
        for (int fm = 0; fm < 4; fm++)
#pragma unroll
            for (int fn = 0; fn < 4; fn++) {
                int col = wn * 64 + fn * 16 + lr;
                float b = bias[col];
#pragma unroll
                for (int q = 0; q < 4; q++) {
                    int r = row0 + fm * 16 + lg * 4 + q;
                    size_t idx = (size_t)r * 512 + col;
                    P[idx] *= sigf(acc[fm][fn][q] + b);
                }
            }
    }
}

// ---------------------------------------------------------------------------
// gemm512: out = A(N,K) @ W(M,K).T, 64x128 tile, 512 threads, float4 reads.
// EPI 0: plain store   EPI 2: softplus(v + bias[c])
// ---------------------------------------------------------------------------
template <int EPI>
__global__ __launch_bounds__(512) void gemm512(
    const float* A, const float* W, const float* bias,
    float* out0, int K, int ldo, int colbase)
{
    __shared__ float As[32][68];
    __shared__ float Wt[32][132];
    const int tid = threadIdx.x;
    const int row0 = blockIdx.x * 64;
    const int col0 = colbase + blockIdx.y * 128;
    const int tr = (tid & 15) * 4;
    const int tc = (tid >> 4) * 4;
    float acc[4][4];
#pragma unroll
    for (int i = 0; i < 4; i++)
#pragma unroll
        for (int j = 0; j < 4; j++) acc[i][j] = 0.f;

    for (int k0 = 0; k0 < K; k0 += 32) {
        __syncthreads();
        for (int i = tid; i < 64 * 32; i += 512) {
            int l = i >> 5, k = i & 31;
            As[k][l] = A[(size_t)(row0 + l) * K + k0 + k];
        }
        {
            int n = tid >> 2, kq = (tid & 3) * 8;
            const float* wp = W + (size_t)(col0 + n) * K + k0 + kq;
            float4 w0 = *(const float4*)wp, w1 = *(const float4*)(wp + 4);
            Wt[kq + 0][n] = w0.x; Wt[kq + 1][n] = w0.y;
            Wt[kq + 2][n] = w0.z; Wt[kq + 3][n] = w0.w;
            Wt[kq + 4][n] = w1.x; Wt[kq + 5][n] = w1.y;
            Wt[kq + 6][n] = w1.z; Wt[kq + 7][n] = w1.w;
        }
        __syncthreads();
#pragma unroll 8
        for (int kk = 0; kk < 32; kk++) {
            float4 a = *(const float4*)&As[kk][tr];
            float4 b = *(const float4*)&Wt[kk][tc];
            acc[0][0] += a.x*b.x; acc[0][1] += a.x*b.y; acc[0][2] += a.x*b.z; acc[0][3] += a.x*b.w;
            acc[1][0] += a.y*b.x; acc[1][1] += a.y*b.y; acc[1][2] += a.y*b.z; acc[1][3] += a.y*b.w;
            acc[2][0] += a.z*b.x; acc[2][1] += a.z*b.y; acc[2][2] += a.z*b.z; acc[2][3] += a.z*b.w;
            acc[3][0] += a.w*b.x; acc[3][1] += a.w*b.y; acc[3][2] += a.w*b.z; acc[3][3] += a.w*b.w;
        }
    }
#pragma unroll
    for (int i = 0; i < 4; i++) {
        int r = row0 + tr + i;
#pragma unroll
        for (int j = 0; j < 4; j++) {
            int c = col0 + tc + j;
            float vv = acc[i][j];
            if (EPI == 2) {
                float s = vv + bias[c];
                out0[(size_t)r * ldo + (c - colbase)] =
                    fmaxf(s, 0.f) + log1pf(expf(-fabsf(s)));
            } else {
                out0[(size_t)r * ldo + (c - colbase)] = vv;
            }
        }
    }
}

// ---------------------------------------------------------------------------
// Small GEMM for x_proj (32 cols), 256 threads (round-5 structure).
// ---------------------------------------------------------------------------
__global__ __launch_bounds__(256) void gemm_nt32(
    const float* A, const float* W, float* out0, int K, int ldo)
{
    __shared__ float As[16][65];
    __shared__ float Ws[16][33];
    const int tid = threadIdx.x;
    const int row0 = blockIdx.x * 64;
    const int tr = (tid / 16) * 4;
    const int tc = (tid % 16) * 2;
    float acc[4][2];
#pragma unroll
    for (int i = 0; i < 4; i++) { acc[i][0] = 0.f; acc[i][1] = 0.f; }
    for (int k0 = 0; k0 < K; k0 += 16) {
        __syncthreads();
        for (int i = tid; i < 64 * 16; i += 256) {
            int m = i / 16, k = i % 16;
            As[k][m] = A[(size_t)(row0 + m) * K + k0 + k];
        }
        for (int i = tid; i < 32 * 16; i += 256) {
            int n = i / 16, k = i % 16;
            Ws[k][n] = W[(size_t)n * K + k0 + k];
        }
        __syncthreads();
#pragma unroll
        for (int kk = 0; kk < 16; kk++) {
            float a[4], b[2];
#pragma unroll
            for (int i = 0; i < 4; i++) a[i] = As[kk][tr + i];
            b[0] = Ws[kk][tc]; b[1] = Ws[kk][tc + 1];
#pragma unroll
            for (int i = 0; i < 4; i++) { acc[i][0] += a[i] * b[0]; acc[i][1] += a[i] * b[1]; }
        }
    }
#pragma unroll
    for (int i = 0; i < 4; i++) {
        int r = row0 + tr + i;
        out0[(size_t)r * ldo + tc] = acc[i][0];
        out0[(size_t)r * ldo + tc + 1] = acc[i][1];
    }
}

// ---------------------------------------------------------------------------
// Selective scan (per 128-channel quarter), 3-pass chunked. (round-5, passed)
// ---------------------------------------------------------------------------
__global__ __launch_bounds__(128) void scan_pass1(
    const float* delta_q, const float* u_full, const float* xdbl,
    const float* A_log, int dbase, float* h_end, float* Ssum)
{
    int c = blockIdx.x;
    int dl = threadIdx.x;
    int d = dbase + dl;
    float As[16];
#pragma unroll
    for (int s = 0; s < 16; s++) As[s] = -expf(A_log[d * 16 + s]);
    float h[16];
#pragma unroll
    for (int s = 0; s < 16; s++) h[s] = 0.f;
    float S = 0.f;
    __shared__ float Bs[CHUNK][17];
    int tbase = c * CHUNK;
    for (int i = dl; i < CHUNK * 16; i += 128) {
        int r = i >> 4, s = i & 15;
        Bs[r][s] = xdbl[(size_t)(tbase + r) * 32 + s];
    }
    __syncthreads();
    for (int tl = 0; tl < CHUNK; tl++) {
        size_t t = (size_t)tbase + tl;
        float de = delta_q[t * QCH + dl];
        float uu = u_full[t * DI + d];
        float du = de * uu;
        S += de;
#pragma unroll
        for (int s = 0; s < 16; s++)
            h[s] = __expf(de * As[s]) * h[s] + du * Bs[tl][s];
    }
    size_t base = ((size_t)c * QCH + dl) * 16;
#pragma unroll
    for (int s = 0; s < 16; s++) h_end[base + s] = h[s];
    Ssum[(size_t)c * QCH + dl] = S;
}

__global__ void scan_pass2(const float* h_end, const float* Ssum,
                           const float* A_log, int dbase, float* initS)
{
    int idx = blockIdx.x * blockDim.x + threadIdx.x;   // 0..2047 = dl*16+s
    int dl = idx >> 4;
    float As = -expf(A_log[(dbase + dl) * 16 + (idx & 15)]);
    float carry = 0.f;
    for (int c = 0; c < NCHUNK; c++) {
        initS[(size_t)c * (QCH * 16) + idx] = carry;
        float P = __expf(As * Ssum[(size_t)c * QCH + dl]);
        carry = P * carry + h_end[(size_t)c * (QCH * 16) + idx];
    }
}

__global__ __launch_bounds__(128) void scan_pass3(
    const float* delta_q, const float* u_full, const float* xdbl,
    const float* A_log, int dbase, const float* initS, const float* Dp,
    float* wg_ymod)
{
    int c = blockIdx.x;
    int dl = threadIdx.x;
    int d = dbase + dl;
    float As[16];
#pragma unroll
    for (int s = 0; s < 16; s++) As[s] = -expf(A_log[d * 16 + s]);
    float h[16];
#pragma unroll
    for (int s = 0; s < 16; s++)
        h[s] = initS[((size_t)c * QCH + dl) * 16 + s];
    float Dd = Dp[d];
    __shared__ float Bs[CHUNK][17];
    __shared__ float Cs[CHUNK][17];
    int tbase = c * CHUNK;
    for (int i = dl; i < CHUNK * 16; i += 128) {
        int r = i >> 4, s = i & 15;
        Bs[r][s] = xdbl[(size_t)(tbase + r) * 32 + s];
        Cs[r][s] = xdbl[(size_t)(tbase + r) * 32 + 16 + s];
    }
    __syncthreads();
    for (int tl = 0; tl < CHUNK; tl++) {
        size_t t = (size_t)tbase + tl;
        float de = delta_q[t * QCH + dl];
        float uu = u_full[t * DI + d];
        float du = de * uu;
        float y = Dd * uu;
#pragma unroll
        for (int s = 0; s < 16; s++) {
            h[s] = __expf(de * As[s]) * h[s] + du * Bs[tl][s];
            y += h[s] * Cs[tl][s];
        }
        wg_ymod[t * DI + d] = y * wg_ymod[t * DI + d];   // y * w_gate, in place
    }
}

// ---------------------------------------------------------------------------
extern "C" void kernel_launch(void* const* d_in, const int* in_sizes, int n_in,
                              void* d_out, int out_size, void* d_ws, size_t ws_size,
                              hipStream_t stream)
{
    const float* x         = (const float*)d_in[0];
    const float* guidance  = (const float*)d_in[1];
    const float* in_proj_w = (const float*)d_in[2];
    const float* conv_w    = (const float*)d_in[3];
    const float* conv_b    = (const float*)d_in[4];
    const float* x_proj_w  = (const float*)d_in[5];
    const float* dt_proj_w = (const float*)d_in[6];
    const float* dt_proj_b = (const float*)d_in[7];
    const float* gg1_w     = (const float*)d_in[8];
    const float* gg1_b     = (const float*)d_in[9];
    const float* ln_g      = (const float*)d_in[10];
    const float* ln_b      = (const float*)d_in[11];
    const float* gg2_w     = (const float*)d_in[12];
    const float* gg2_b     = (const float*)d_in[13];
    const float* A_log     = (const float*)d_in[14];
    const float* Dp        = (const float*)d_in[15];
    const float* out_proj_w= (const float*)d_in[16];
    float* out = (float*)d_out;

    // ws: two N x 512 fp32 buffers = 256 MiB exactly.
    float* P1 = (float*)d_ws;                    // x_mod (scan u)
    float* P2 = P1 + (size_t)NTOK * DI;          // w_gate -> y_mod (in place)

    // d_out as pre-final scratch (final GEMM overwrites all).
    float* ob      = (float*)d_out;
    float* delta_q = ob;                                  // N x 128   (32 MiB)
    float* xdbl    = ob + (size_t)NTOK * QCH;             // N x 32    (8 MiB)
    float* h_end   = ob + (size_t)NTOK * (QCH + 32);      // 4 MiB
    float* Ssum    = h_end + (size_t)NCHUNK * QCH * DS;   // 0.25 MiB
    float* initS   = Ssum + (size_t)NCHUNK * QCH;         // 4 MiB
    // bf16 hi/lo splits in the free tail of d_out:
    //   Wg  (gg2_w blocks)   131072 packets = 2 MiB
    //   Wg2 (in_proj_w)       65536 packets = 1 MiB
    unsigned short* Wg  = (unsigned short*)(initS + (size_t)NCHUNK * QCH * DS);
    unsigned short* Wg2 = Wg + (size_t)131072 * 8;

    // 0. W split-precision preps (independent of everything else)
    wprep_kernel<<<512, 256, 0, stream>>>(gg2_w, Wg);
    wprep_inproj<<<256, 256, 0, stream>>>(in_proj_w, Wg2);
    // 1. in_proj + conv + silu (bf16x3 MFMA) -> P1 = silu(conv(x_in)), P2 = silu(z)
    in_conv_mfma<<<NTOK / 64, 512, 0, stream>>>(
        x, Wg2, conv_w, conv_b, P1, P2);
    // 2. gates (barrier-free bf16x3 MFMA): P1 *= gate_in, P2 *= gate_out
    gates_mfma_kernel<<<NTOK / 64, 512, 0, stream>>>(
        guidance, gg1_w, gg1_b, ln_g, ln_b, Wg, gg2_b, P1, P2);
    // 3. xdbl = x_mod @ x_proj_w.T  (B|C)
    gemm_nt32<<<NTOK / 64, 256, 0, stream>>>(P1, x_proj_w, xdbl, DI, 32);
    // 4. per 128-channel quarter: delta GEMM + 3-pass scan (y_mod over P2)
    for (int q = 0; q < 4; q++) {
        int dbase = q * QCH;
        gemm512<2><<<dim3(NTOK / 64, 1), 512, 0, stream>>>(
            P1, dt_proj_w, dt_proj_b, delta_q, DI, QCH, dbase);
        scan_pass1<<<NCHUNK, 128, 0, stream>>>(
            delta_q, P1, xdbl, A_log, dbase, h_end, Ssum);
        scan_pass2<<<(QCH * DS) / 256, 256, 0, stream>>>(
            h_end, Ssum, A_log, dbase, initS);
        scan_pass3<<<NCHUNK, 128, 0, stream>>>(
            delta_q, P1, xdbl, A_log, dbase, initS, Dp, P2);
    }
    // 5. out = y_mod @ out_proj_w.T  (overwrites all d_out scratch)
    gemm512<0><<<dim3(NTOK / 64, 2), 512, 0, stream>>>(
        P2, out_proj_w, nullptr, out, DI, DMODEL, 0);
}

// Round 4
// 2576.992 us; speedup vs baseline: 1.7466x; 1.1605x over previous
//
#include <hip/hip_runtime.h>
#include <math.h>

#define NTOK 65536
#define DMODEL 256
#define DI 512
#define DS 16
#define CHUNK 128
#define NCHUNK (NTOK / CHUNK)   // 512
#define QCH 128                 // channels per scan quarter

typedef __bf16 bf16x8 __attribute__((ext_vector_type(8)));
typedef float  f32x4  __attribute__((ext_vector_type(4)));

__device__ __forceinline__ float sigf(float x) { return 1.0f / (1.0f + expf(-x)); }

// ---------------------------------------------------------------------------
// wprep_kernel: split the two used 512x512 blocks of gg2_w into hi/lo bf16,
// fragment packet order (verified round 1/2).
// ---------------------------------------------------------------------------
__global__ __launch_bounds__(256) void wprep_kernel(
    const float* gg2_w, unsigned short* Wg)
{
    int p = blockIdx.x * 256 + threadIdx.x;   // 0 .. 131071
    int lg = p & 3;
    int c  = (p >> 2) & 511;
    int hl = (p >> 11) & 1;
    int kc = (p >> 12) & 15;
    int gm = p >> 16;
    int row = gm * 1024 + c;
    const float* src = gg2_w + (size_t)row * 512 + kc * 32 + lg * 8;
    union { unsigned short u[8]; float4 f; } outv;
#pragma unroll
    for (int j = 0; j < 8; j++) {
        float x = src[j];
        __bf16 h = (__bf16)x;
        union { __bf16 b; unsigned short us; } cv;
        if (hl) cv.b = (__bf16)(x - (float)h); else cv.b = h;
        outv.u[j] = cv.us;
    }
    *(float4*)(Wg + (size_t)p * 8) = outv.f;
}

// ---------------------------------------------------------------------------
// wprep_inproj: split in_proj_w (1024 x 256), fragment order (verified r2).
// ---------------------------------------------------------------------------
__global__ __launch_bounds__(256) void wprep_inproj(
    const float* in_proj_w, unsigned short* Wg2)
{
    int p = blockIdx.x * 256 + threadIdx.x;   // 0 .. 65535
    int lg = p & 3;
    int c  = (p >> 2) & 511;
    int hl = (p >> 11) & 1;
    int kc = (p >> 12) & 7;
    int gm = p >> 15;
    const float* src = in_proj_w + (size_t)(gm * 512 + c) * 256 + kc * 32 + lg * 8;
    union { unsigned short u[8]; float4 f; } outv;
#pragma unroll
    for (int j = 0; j < 8; j++) {
        float x = src[j];
        __bf16 h = (__bf16)x;
        union { __bf16 b; unsigned short us; } cv;
        if (hl) cv.b = (__bf16)(x - (float)h); else cv.b = h;
        outv.u[j] = cv.us;
    }
    *(float4*)(Wg2 + (size_t)p * 8) = outv.f;
}

// ---------------------------------------------------------------------------
// wprep_dt: split dt_proj_w (512 x 512) into hi/lo bf16 packets, per-quarter:
//   p = (((q*16 + kc)*2 + hl)*128 + c)*4 + lg
//   element j = dt_proj_w[q*128 + c][kc*32 + lg*8 + j]
// ---------------------------------------------------------------------------
__global__ __launch_bounds__(256) void wprep_dt(
    const float* dt_proj_w, unsigned short* Wdt)
{
    int p = blockIdx.x * 256 + threadIdx.x;   // 0 .. 65535
    int lg = p & 3;
    int c  = (p >> 2) & 127;
    int hl = (p >> 9) & 1;
    int kc = (p >> 10) & 15;
    int q  = p >> 14;
    const float* src = dt_proj_w + (size_t)(q * 128 + c) * 512 + kc * 32 + lg * 8;
    union { unsigned short u[8]; float4 f; } outv;
#pragma unroll
    for (int j = 0; j < 8; j++) {
        float x = src[j];
        __bf16 h = (__bf16)x;
        union { __bf16 b; unsigned short us; } cv;
        if (hl) cv.b = (__bf16)(x - (float)h); else cv.b = h;
        outv.u[j] = cv.us;
    }
    *(float4*)(Wdt + (size_t)p * 8) = outv.f;
}

// ---------------------------------------------------------------------------
// wprep_out: split out_proj_w (256 x 512) into hi/lo bf16 packets:
//   p = ((kc*2 + hl)*256 + c)*4 + lg
//   element j = out_proj_w[c][kc*32 + lg*8 + j]
// Written into the (then-dead) head of P1 just before the final GEMM.
// ---------------------------------------------------------------------------
__global__ __launch_bounds__(256) void wprep_out(
    const float* out_proj_w, unsigned short* Wout)
{
    int p = blockIdx.x * 256 + threadIdx.x;   // 0 .. 32767
    int lg = p & 3;
    int c  = (p >> 2) & 255;
    int hl = (p >> 10) & 1;
    int kc = p >> 11;
    const float* src = out_proj_w + (size_t)c * 512 + kc * 32 + lg * 8;
    union { unsigned short u[8]; float4 f; } outv;
#pragma unroll
    for (int j = 0; j < 8; j++) {
        float x = src[j];
        __bf16 h = (__bf16)x;
        union { __bf16 b; unsigned short us; } cv;
        if (hl) cv.b = (__bf16)(x - (float)h); else cv.b = h;
        outv.u[j] = cv.us;
    }
    *(float4*)(Wout + (size_t)p * 8) = outv.f;
}

// ---------------------------------------------------------------------------
// in_conv_mfma: bf16x3 streaming-MFMA in_proj + conv + silu (round-3 verified)
// ---------------------------------------------------------------------------
#define MFMA_CHUNK(NFM, KC, WH, WL)                                           \
    _Pragma("unroll")                                                         \
    for (int fm = 0; fm < NFM; fm++) {                                        \
        int t = (fm < 4) ? (fm * 16 + lr) : (64 + lr);                        \
        int pidx = (t * 32 + (((KC) * 4 + lg) ^ (t & 7))) * 8;                \
        bf16x8 ah = *(const bf16x8*)&AhL[pidx];                               \
        bf16x8 al = *(const bf16x8*)&AlL[pidx];                               \
        _Pragma("unroll")                                                     \
        for (int fn = 0; fn < 4; fn++) {                                      \
            acc[fm][fn] = __builtin_amdgcn_mfma_f32_16x16x32_bf16(ah, WH[fn], acc[fm][fn], 0, 0, 0); \
            acc[fm][fn] = __builtin_amdgcn_mfma_f32_16x16x32_bf16(ah, WL[fn], acc[fm][fn], 0, 0, 0); \
            acc[fm][fn] = __builtin_amdgcn_mfma_f32_16x16x32_bf16(al, WH[fn], acc[fm][fn], 0, 0, 0); \
        }                                                                     \
    }

__global__ __launch_bounds__(512, 2) void in_conv_mfma(
    const float* x, const unsigned short* Wg2, const float* conv_w,
    const float* conv_b, float* P1, float* P2)
{
    __shared__ __align__(16) unsigned short smem[2 * 80 * 256];  // 80 KiB
    unsigned short* AhL = smem;
    unsigned short* AlL = smem + 80 * 256;
    float* xs = (float*)smem;          // repurposed: [8 waves][68][33] fp32

    const int tid = threadIdx.x;
    const int row0 = blockIdx.x * 64;
    const int l  = tid & 63;
    const int wn = tid >> 6;           // wave id / col-slice
    const int lr = l & 15;
    const int lg = l >> 4;

    // ---- Phase A: stage x split hi/lo (rows 0..63 main, 64..67 halo, rest 0)
    for (int i = tid; i < 80 * 32; i += 512) {
        int t = i >> 5, k8 = i & 31;
        float xv[8];
#pragma unroll
        for (int j = 0; j < 8; j++) xv[j] = 0.f;
        if (t < 68) {
            int gr = (t < 64) ? (row0 + t) : (row0 - 68 + t);
            if (gr >= 0) {
                float4 a0 = *(const float4*)(x + (size_t)gr * 256 + k8 * 8);
                float4 a1 = *(const float4*)(x + (size_t)gr * 256 + k8 * 8 + 4);
                xv[0]=a0.x; xv[1]=a0.y; xv[2]=a0.z; xv[3]=a0.w;
                xv[4]=a1.x; xv[5]=a1.y; xv[6]=a1.z; xv[7]=a1.w;
            }
        }
        bf16x8 ho, lo;
#pragma unroll
        for (int j = 0; j < 8; j++) {
            __bf16 hh = (__bf16)xv[j];
            ho[j] = hh;
            lo[j] = (__bf16)(xv[j] - (float)hh);
        }
        int pidx = (t * 32 + (k8 ^ (t & 7))) * 8;
        *(bf16x8*)&AhL[pidx] = ho;
        *(bf16x8*)&AlL[pidx] = lo;
    }
    __syncthreads();

    auto loadW = [&](int gm, int kc, bf16x8 (&wh)[4], bf16x8 (&wl)[4]) {
        const unsigned short* bh = Wg2 + (size_t)(((gm * 8 + kc) * 2 + 0) * 2048) * 8;
        const unsigned short* bl = Wg2 + (size_t)(((gm * 8 + kc) * 2 + 1) * 2048) * 8;
        const int pk = (wn * 64 + lr) * 4 + lg;
#pragma unroll
        for (int fn = 0; fn < 4; fn++) {
            wh[fn] = *(const bf16x8*)(bh + (size_t)(pk + fn * 64) * 8);
            wl[fn] = *(const bf16x8*)(bl + (size_t)(pk + fn * 64) * 8);
        }
    };

    // ---- z half (gm=1): 4 fm tiles, direct silu epilogue ----
    {
        f32x4 acc[4][4];
#pragma unroll
        for (int fm = 0; fm < 4; fm++)
#pragma unroll
            for (int fn = 0; fn < 4; fn++)
                acc[fm][fn] = (f32x4){0.f, 0.f, 0.f, 0.f};
        bf16x8 whA[4], wlA[4], whB[4], wlB[4];
        loadW(1, 0, whA, wlA);
#pragma unroll
        for (int kc = 0; kc < 8; kc += 2) {
            loadW(1, kc + 1, whB, wlB);
            MFMA_CHUNK(4, kc, whA, wlA)
            if (kc + 2 < 8) loadW(1, kc + 2, whA, wlA);
            MFMA_CHUNK(4, kc + 1, whB, wlB)
        }
#pragma unroll
        for (int fm = 0; fm < 4; fm++)
#pragma unroll
            for (int fn = 0; fn < 4; fn++) {
                int col = wn * 64 + fn * 16 + lr;
#pragma unroll
                for (int q = 0; q < 4; q++) {
                    int r = row0 + fm * 16 + lg * 4 + q;
                    float vz = acc[fm][fn][q];
                    P2[(size_t)r * 512 + col] = vz * sigf(vz);
                }
            }
    }

    // ---- x_in half (gm=0): 5 fm tiles (halo), conv epilogue ----
    {
        f32x4 acc[5][4];
#pragma unroll
        for (int fm = 0; fm < 5; fm++)
#pragma unroll
            for (int fn = 0; fn < 4; fn++)
                acc[fm][fn] = (f32x4){0.f, 0.f, 0.f, 0.f};
        bf16x8 whA[4], wlA[4], whB[4], wlB[4];
        loadW(0, 0, whA, wlA);
#pragma unroll
        for (int kc = 0; kc < 8; kc += 2) {
            loadW(0, kc + 1, whB, wlB);
            MFMA_CHUNK(5, kc, whA, wlA)
            if (kc + 2 < 8) loadW(0, kc + 2, whA, wlA);
            MFMA_CHUNK(5, kc + 1, whB, wlB)
        }

        __syncthreads();                       // all waves done reading A-LDS
        float* xsw = xs + wn * (68 * 33);      // per-wave slab (wave-private)
        const int c_local = l & 31;
        const int rbase = (l >> 5) * 32;
#pragma unroll
        for (int h = 0; h < 2; h++) {
            if (h) __syncthreads();            // uniform; protects slab reuse
#pragma unroll
            for (int fm = 0; fm < 5; fm++)
#pragma unroll
                for (int ff = 0; ff < 2; ff++) {
                    int fn = h * 2 + ff;
#pragma unroll
                    for (int q = 0; q < 4; q++) {
                        if (fm < 4) {
                            int rr = 4 + fm * 16 + lg * 4 + q;
                            xsw[rr * 33 + ff * 16 + lr] = acc[fm][fn][q];
                        } else if (lg == 0) {
                            xsw[q * 33 + ff * 16 + lr] = acc[fm][fn][q];
                        }
                    }
                }
            asm volatile("s_waitcnt lgkmcnt(0)" ::: "memory");
            int cg = wn * 64 + h * 32 + c_local;
            float w0 = conv_w[cg * 4 + 0], w1 = conv_w[cg * 4 + 1];
            float w2 = conv_w[cg * 4 + 2], w3 = conv_w[cg * 4 + 3];
            float cb = conv_b[cg];
            float s0 = xsw[(rbase + 1) * 33 + c_local];
            float s1 = xsw[(rbase + 2) * 33 + c_local];
            float s2 = xsw[(rbase + 3) * 33 + c_local];
#pragma unroll
            for (int i = 0; i < 32; i++) {
                float s3 = xsw[(rbase + 4 + i) * 33 + c_local];
                float cv = cb + w0 * s0 + w1 * s1 + w2 * s2 + w3 * s3;
                cv = cv * sigf(cv);
                P1[(size_t)(row0 + rbase + i) * 512 + cg] = cv;
                s0 = s1; s1 = s2; s2 = s3;
            }
        }
    }
}

// ---------------------------------------------------------------------------
// gates_mfma_kernel v2: barrier-free streaming MFMA. (round-2 verified)
// ---------------------------------------------------------------------------
__global__ __launch_bounds__(512, 2) void gates_mfma_kernel(
    const float* guidance, const float* gg1_w, const float* gg1_b,
    const float* ln_g, const float* ln_b,
    const unsigned short* Wg, const float* gg2_b,
    float* P1, float* P2)
{
    __shared__ unsigned short AhL[64 * 512];   // 64 KiB  [tok][k] swizzled
    __shared__ unsigned short AlL[64 * 512];   // 64 KiB
    __shared__ float red_s[64][9], red_q[64][9];

    const int tid = threadIdx.x;
    const int tok = tid & 63;
    const int o   = tid >> 6;        // 0..7 == wave id
    const int row0 = blockIdx.x * 64;

    float g0 = guidance[(size_t)(row0 + tok) * 3 + 0];
    float g1 = guidance[(size_t)(row0 + tok) * 3 + 1];
    float g2 = guidance[(size_t)(row0 + tok) * 3 + 2];
    float v[64];
    float sum = 0.f, sumsq = 0.f;
#pragma unroll
    for (int m = 0; m < 8; m++)
#pragma unroll
        for (int jj = 0; jj < 8; jj++) {
            int d = m * 64 + o * 8 + jj;
            float t = gg1_w[d * 3 + 0] * g0 + gg1_w[d * 3 + 1] * g1 +
                      gg1_w[d * 3 + 2] * g2 + gg1_b[d];
            v[m * 8 + jj] = t;
            sum += t; sumsq += t * t;
        }
    red_s[tok][o] = sum; red_q[tok][o] = sumsq;
    __syncthreads();
    sum = 0.f; sumsq = 0.f;
#pragma unroll
    for (int oo = 0; oo < 8; oo++) { sum += red_s[tok][oo]; sumsq += red_q[tok][oo]; }
    float mu = sum * (1.f / 512.f);
    float var = fmaxf(sumsq * (1.f / 512.f) - mu * mu, 0.f);
    float rstd = 1.f / sqrtf(var + 1e-5f);
#pragma unroll
    for (int m = 0; m < 8; m++) {
        bf16x8 hoct, loct;
#pragma unroll
        for (int jj = 0; jj < 8; jj++) {
            int d = m * 64 + o * 8 + jj;
            float t = (v[m * 8 + jj] - mu) * rstd * ln_g[d] + ln_b[d];
            t = 0.5f * t * (1.f + erff(t * 0.70710678118654752440f));
            __bf16 h = (__bf16)t;
            hoct[jj] = h;
            loct[jj] = (__bf16)(t - (float)h);
        }
        int pidx = ((tok * 64 + (m * 8 + o)) ^ (tok & 7)) * 8;
        *(bf16x8*)&AhL[pidx] = hoct;
        *(bf16x8*)&AlL[pidx] = loct;
    }
    __syncthreads();     // the ONLY barrier before Phase B

    const int l  = tid & 63;
    const int wn = tid >> 6;
    const int lr = l & 15;
    const int lg = l >> 4;

    for (int gm = 0; gm < 2; gm++) {
        f32x4 acc[4][4];
#pragma unroll
        for (int fm = 0; fm < 4; fm++)
#pragma unroll
            for (int fn = 0; fn < 4; fn++)
                acc[fm][fn] = (f32x4){0.f, 0.f, 0.f, 0.f};

        bf16x8 whA[4], wlA[4], whB[4], wlB[4];

        auto loadW = [&](int kc, bf16x8 (&wh)[4], bf16x8 (&wl)[4]) {
            const unsigned short* bh = Wg + (size_t)(((gm * 16 + kc) * 2 + 0) * 2048) * 8;
            const unsigned short* bl = Wg + (size_t)(((gm * 16 + kc) * 2 + 1) * 2048) * 8;
            int pk = (wn * 64 + lr) * 4 + lg;
#pragma unroll
            for (int fn = 0; fn < 4; fn++) {
                wh[fn] = *(const bf16x8*)(bh + (size_t)(pk + fn * 64) * 8);
                wl[fn] = *(const bf16x8*)(bl + (size_t)(pk + fn * 64) * 8);
            }
        };
        auto doChunk = [&](int kc, const bf16x8 (&wh)[4], const bf16x8 (&wl)[4]) {
#pragma unroll
            for (int fm = 0; fm < 4; fm++) {
                int t = fm * 16 + lr;
                int pidx = ((t * 64 + kc * 4 + lg) ^ (lr & 7)) * 8;
                bf16x8 ah = *(const bf16x8*)&AhL[pidx];
                bf16x8 al = *(const bf16x8*)&AlL[pidx];
#pragma unroll
                for (int fn = 0; fn < 4; fn++) {
                    acc[fm][fn] = __builtin_amdgcn_mfma_f32_16x16x32_bf16(
                        ah, wh[fn], acc[fm][fn], 0, 0, 0);
                    acc[fm][fn] = __builtin_amdgcn_mfma_f32_16x16x32_bf16(
                        ah, wl[fn], acc[fm][fn], 0, 0, 0);
                    acc[fm][fn] = __builtin_amdgcn_mfma_f32_16x16x32_bf16(
                        al, wh[fn], acc[fm][fn], 0, 0, 0);
                }
            }
        };

        loadW(0, whA, wlA);
        for (int kc = 0; kc < 16; kc += 2) {
            loadW(kc + 1, whB, wlB);
            doChunk(kc, whA, wlA);
            if (kc + 2 < 16) loadW(kc + 2, whA, wlA);
            doChunk(kc + 1, whB, wlB);
        }

        float* P = gm ? P2 : P1;
        const float* bias = gg2_b + gm * 1024;
#pragma unroll
        for (int fm = 0; fm < 4; fm++)
#pragma unroll
            for (int fn = 0; fn < 4; fn++) {
                int col = wn * 64 + fn * 16 + lr;
                float b = bias[col];
#pragma unroll
                for (int q = 0; q < 4; q++) {
                    int r = row0 + fm * 16 + lg * 4 + q;
                    size_t idx = (size_t)r * 512 + col;
                    P[idx] *= sigf(acc[fm][fn][q] + b);
                }
            }
    }
}

// ---------------------------------------------------------------------------
// dtp_mfma: delta quarter = softplus(P1 @ dt_proj_w[q].T + b), bf16x3 MFMA.
//   Phase A: P1 tile 64x512 hi/lo-split into 128 KiB swizzled LDS, 1 barrier.
//   Phase B: barrier-free; 8 waves as 2(M)x4(N); wave = 32 tok x 32 cols.
// ---------------------------------------------------------------------------
__global__ __launch_bounds__(512, 2) void dtp_mfma(
    const float* A, const unsigned short* Wdt, const float* bias,
    int dbase, float* delta_q)
{
    __shared__ __align__(16) unsigned short AhL[64 * 512];  // 64 KiB
    __shared__ __align__(16) unsigned short AlL[64 * 512];  // 64 KiB
    const int tid = threadIdx.x;
    const int row0 = blockIdx.x * 64;

    for (int i = tid; i < 64 * 64; i += 512) {
        int t = i >> 6, k8 = i & 63;
        const float* src = A + (size_t)(row0 + t) * 512 + k8 * 8;
        float4 a0 = *(const float4*)src, a1 = *(const float4*)(src + 4);
        float xv[8] = {a0.x, a0.y, a0.z, a0.w, a1.x, a1.y, a1.z, a1.w};
        bf16x8 ho, lo;
#pragma unroll
        for (int j = 0; j < 8; j++) {
            __bf16 hh = (__bf16)xv[j];
            ho[j] = hh;
            lo[j] = (__bf16)(xv[j] - (float)hh);
        }
        int pidx = (t * 64 + (k8 ^ (t & 7))) * 8;
        *(bf16x8*)&AhL[pidx] = ho;
        *(bf16x8*)&AlL[pidx] = lo;
    }
    __syncthreads();

    const int l  = tid & 63;
    const int wv = tid >> 6;
    const int wr = wv >> 2;          // 0..1  token half (32 rows)
    const int wc = wv & 3;           // 0..3  col quarter (32 cols)
    const int lr = l & 15;
    const int lg = l >> 4;
    const unsigned short* Wq = Wdt + (size_t)(dbase >> 7) * 16384 * 8;

    f32x4 acc[2][2];
#pragma unroll
    for (int fm = 0; fm < 2; fm++)
#pragma unroll
        for (int fn = 0; fn < 2; fn++)
            acc[fm][fn] = (f32x4){0.f, 0.f, 0.f, 0.f};

    bf16x8 whA[2], wlA[2], whB[2], wlB[2];
    auto loadW = [&](int kc, bf16x8 (&wh)[2], bf16x8 (&wl)[2]) {
        const unsigned short* bh = Wq + (size_t)((kc * 2 + 0) * 512) * 8;
        const unsigned short* bl = Wq + (size_t)((kc * 2 + 1) * 512) * 8;
        int pk = (wc * 32 + lr) * 4 + lg;
#pragma unroll
        for (int fn = 0; fn < 2; fn++) {
            wh[fn] = *(const bf16x8*)(bh + (size_t)(pk + fn * 64) * 8);
            wl[fn] = *(const bf16x8*)(bl + (size_t)(pk + fn * 64) * 8);
        }
    };
    auto doChunk = [&](int kc, const bf16x8 (&wh)[2], const bf16x8 (&wl)[2]) {
#pragma unroll
        for (int fm = 0; fm < 2; fm++) {
            int t = wr * 32 + fm * 16 + lr;
            int pidx = (t * 64 + ((kc * 4 + lg) ^ (t & 7))) * 8;
            bf16x8 ah = *(const bf16x8*)&AhL[pidx];
            bf16x8 al = *(const bf16x8*)&AlL[pidx];
#pragma unroll
            for (int fn = 0; fn < 2; fn++) {
                acc[fm][fn] = __builtin_amdgcn_mfma_f32_16x16x32_bf16(
                    ah, wh[fn], acc[fm][fn], 0, 0, 0);
                acc[fm][fn] = __builtin_amdgcn_mfma_f32_16x16x32_bf16(
                    ah, wl[fn], acc[fm][fn], 0, 0, 0);
                acc[fm][fn] = __builtin_amdgcn_mfma_f32_16x16x32_bf16(
                    al, wh[fn], acc[fm][fn], 0, 0, 0);
            }
        }
    };

    loadW(0, whA, wlA);
    for (int kc = 0; kc < 16; kc += 2) {
        loadW(kc + 1, whB, wlB);
        doChunk(kc, whA, wlA);
        if (kc + 2 < 16) loadW(kc + 2, whA, wlA);
        doChunk(kc + 1, whB, wlB);
    }

#pragma unroll
    for (int fm = 0; fm < 2; fm++)
#pragma unroll
        for (int fn = 0; fn < 2; fn++) {
            int col = wc * 32 + fn * 16 + lr;
            float b = bias[dbase + col];
#pragma unroll
            for (int q = 0; q < 4; q++) {
                int r = row0 + wr * 32 + fm * 16 + lg * 4 + q;
                float s = acc[fm][fn][q] + b;
                delta_q[(size_t)r * 128 + col] =
                    fmaxf(s, 0.f) + log1pf(expf(-fabsf(s)));
            }
        }
}

// ---------------------------------------------------------------------------
// outp_mfma: out = P2 @ out_proj_w.T (256 cols), bf16x3 MFMA.
//   Same structure; 8 waves as 2(M)x4(N); wave = 32 tok x 64 cols.
// ---------------------------------------------------------------------------
__global__ __launch_bounds__(512, 2) void outp_mfma(
    const float* A, const unsigned short* Wout, float* out)
{
    __shared__ __align__(16) unsigned short AhL[64 * 512];  // 64 KiB
    __shared__ __align__(16) unsigned short AlL[64 * 512];  // 64 KiB
    const int tid = threadIdx.x;
    const int row0 = blockIdx.x * 64;

    for (int i = tid; i < 64 * 64; i += 512) {
        int t = i >> 6, k8 = i & 63;
        const float* src = A + (size_t)(row0 + t) * 512 + k8 * 8;
        float4 a0 = *(const float4*)src, a1 = *(const float4*)(src + 4);
        float xv[8] = {a0.x, a0.y, a0.z, a0.w, a1.x, a1.y, a1.z, a1.w};
        bf16x8 ho, lo;
#pragma unroll
        for (int j = 0; j < 8; j++) {
            __bf16 hh = (__bf16)xv[j];
            ho[j] = hh;
            lo[j] = (__bf16)(xv[j] - (float)hh);
        }
        int pidx = (t * 64 + (k8 ^ (t & 7))) * 8;
        *(bf16x8*)&AhL[pidx] = ho;
        *(bf16x8*)&AlL[pidx] = lo;
    }
    __syncthreads();

    const int l  = tid & 63;
    const int wv = tid >> 6;
    const int wr = wv >> 2;          // 0..1  token half (32 rows)
    const int wc = wv & 3;           // 0..3  col slice (64 cols)
    const int lr = l & 15;
    const int lg = l >> 4;

    f32x4 acc[2][4];
#pragma unroll
    for (int fm = 0; fm < 2; fm++)
#pragma unroll
        for (int fn = 0; fn < 4; fn++)
            acc[fm][fn] = (f32x4){0.f, 0.f, 0.f, 0.f};

    bf16x8 whA[4], wlA[4], whB[4], wlB[4];
    auto loadW = [&](int kc, bf16x8 (&wh)[4], bf16x8 (&wl)[4]) {
        const unsigned short* bh = Wout + (size_t)((kc * 2 + 0) * 1024) * 8;
        const unsigned short* bl = Wout + (size_t)((kc * 2 + 1) * 1024) * 8;
        int pk = (wc * 64 + lr) * 4 + lg;
#pragma unroll
        for (int fn = 0; fn < 4; fn++) {
            wh[fn] = *(const bf16x8*)(bh + (size_t)(pk + fn * 64) * 8);
            wl[fn] = *(const bf16x8*)(bl + (size_t)(pk + fn * 64) * 8);
        }
    };
    auto doChunk = [&](int kc, const bf16x8 (&wh)[4], const bf16x8 (&wl)[4]) {
#pragma unroll
        for (int fm = 0; fm < 2; fm++) {
            int t = wr * 32 + fm * 16 + lr;
            int pidx = (t * 64 + ((kc * 4 + lg) ^ (t & 7))) * 8;
            bf16x8 ah = *(const bf16x8*)&AhL[pidx];
            bf16x8 al = *(const bf16x8*)&AlL[pidx];
#pragma unroll
            for (int fn = 0; fn < 4; fn++) {
                acc[fm][fn] = __builtin_amdgcn_mfma_f32_16x16x32_bf16(
                    ah, wh[fn], acc[fm][fn], 0, 0, 0);
                acc[fm][fn] = __builtin_amdgcn_mfma_f32_16x16x32_bf16(
                    ah, wl[fn], acc[fm][fn], 0, 0, 0);
                acc[fm][fn] = __builtin_amdgcn_mfma_f32_16x16x32_bf16(
                    al, wh[fn], acc[fm][fn], 0, 0, 0);
            }
        }
    };

    loadW(0, whA, wlA);
    for (int kc = 0; kc < 16; kc += 2) {
        loadW(kc + 1, whB, wlB);
        doChunk(kc, whA, wlA);
        if (kc + 2 < 16) loadW(kc + 2, whA, wlA);
        doChunk(kc + 1, whB, wlB);
    }

#pragma unroll
    for (int fm = 0; fm < 2; fm++)
#pragma unroll
        for (int fn = 0; fn < 4; fn++) {
            int col = wc * 64 + fn * 16 + lr;
#pragma unroll
            for (int q = 0; q < 4; q++) {
                int r = row0 + wr * 32 + fm * 16 + lg * 4 + q;
                out[(size_t)r * 256 + col] = acc[fm][fn][q];
            }
        }
}

// ---------------------------------------------------------------------------
// Small GEMM for x_proj (32 cols), 256 threads (round-5 structure).
// ---------------------------------------------------------------------------
__global__ __launch_bounds__(256) void gemm_nt32(
    const float* A, const float* W, float* out0, int K, int ldo)
{
    __shared__ float As[16][65];
    __shared__ float Ws[16][33];
    const int tid = threadIdx.x;
    const int row0 = blockIdx.x * 64;
    const int tr = (tid / 16) * 4;
    const int tc = (tid % 16) * 2;
    float acc[4][2];
#pragma unroll
    for (int i = 0; i < 4; i++) { acc[i][0] = 0.f; acc[i][1] = 0.f; }
    for (int k0 = 0; k0 < K; k0 += 16) {
        __syncthreads();
        for (int i = tid; i < 64 * 16; i += 256) {
            int m = i / 16, k = i % 16;
            As[k][m] = A[(size_t)(row0 + m) * K + k0 + k];
        }
        for (int i = tid; i < 32 * 16; i += 256) {
            int n = i / 16, k = i % 16;
            Ws[k][n] = W[(size_t)n * K + k0 + k];
        }
        __syncthreads();
#pragma unroll
        for (int kk = 0; kk < 16; kk++) {
            float a[4], b[2];
#pragma unroll
            for (int i = 0; i < 4; i++) a[i] = As[kk][tr + i];
            b[0] = Ws[kk][tc]; b[1] = Ws[kk][tc + 1];
#pragma unroll
            for (int i = 0; i < 4; i++) { acc[i][0] += a[i] * b[0]; acc[i][1] += a[i] * b[1]; }
        }
    }
#pragma unroll
    for (int i = 0; i < 4; i++) {
        int r = row0 + tr + i;
        out0[(size_t)r * ldo + tc] = acc[i][0];
        out0[(size_t)r * ldo + tc + 1] = acc[i][1];
    }
}

// ---------------------------------------------------------------------------
// Selective scan (per 128-channel quarter), 3-pass chunked. (round-5, passed)
// ---------------------------------------------------------------------------
__global__ __launch_bounds__(128) void scan_pass1(
    const float* delta_q, const float* u_full, const float* xdbl,
    const float* A_log, int dbase, float* h_end, float* Ssum)
{
    int c = blockIdx.x;
    int dl = threadIdx.x;
    int d = dbase + dl;
    float As[16];
#pragma unroll
    for (int s = 0; s < 16; s++) As[s] = -expf(A_log[d * 16 + s]);
    float h[16];
#pragma unroll
    for (int s = 0; s < 16; s++) h[s] = 0.f;
    float S = 0.f;
    __shared__ float Bs[CHUNK][17];
    int tbase = c * CHUNK;
    for (int i = dl; i < CHUNK * 16; i += 128) {
        int r = i >> 4, s = i & 15;
        Bs[r][s] = xdbl[(size_t)(tbase + r) * 32 + s];
    }
    __syncthreads();
    for (int tl = 0; tl < CHUNK; tl++) {
        size_t t = (size_t)tbase + tl;
        float de = delta_q[t * QCH + dl];
        float uu = u_full[t * DI + d];
        float du = de * uu;
        S += de;
#pragma unroll
        for (int s = 0; s < 16; s++)
            h[s] = __expf(de * As[s]) * h[s] + du * Bs[tl][s];
    }
    size_t base = ((size_t)c * QCH + dl) * 16;
#pragma unroll
    for (int s = 0; s < 16; s++) h_end[base + s] = h[s];
    Ssum[(size_t)c * QCH + dl] = S;
}

__global__ void scan_pass2(const float* h_end, const float* Ssum,
                           const float* A_log, int dbase, float* initS)
{
    int idx = blockIdx.x * blockDim.x + threadIdx.x;   // 0..2047 = dl*16+s
    int dl = idx >> 4;
    float As = -expf(A_log[(dbase + dl) * 16 + (idx & 15)]);
    float carry = 0.f;
    for (int c = 0; c < NCHUNK; c++) {
        initS[(size_t)c * (QCH * 16) + idx] = carry;
        float P = __expf(As * Ssum[(size_t)c * QCH + dl]);
        carry = P * carry + h_end[(size_t)c * (QCH * 16) + idx];
    }
}

__global__ __launch_bounds__(128) void scan_pass3(
    const float* delta_q, const float* u_full, const float* xdbl,
    const float* A_log, int dbase, const float* initS, const float* Dp,
    float* wg_ymod)
{
    int c = blockIdx.x;
    int dl = threadIdx.x;
    int d = dbase + dl;
    float As[16];
#pragma unroll
    for (int s = 0; s < 16; s++) As[s] = -expf(A_log[d * 16 + s]);
    float h[16];
#pragma unroll
    for (int s = 0; s < 16; s++)
        h[s] = initS[((size_t)c * QCH + dl) * 16 + s];
    float Dd = Dp[d];
    __shared__ float Bs[CHUNK][17];
    __shared__ float Cs[CHUNK][17];
    int tbase = c * CHUNK;
    for (int i = dl; i < CHUNK * 16; i += 128) {
        int r = i >> 4, s = i & 15;
        Bs[r][s] = xdbl[(size_t)(tbase + r) * 32 + s];
        Cs[r][s] = xdbl[(size_t)(tbase + r) * 32 + 16 + s];
    }
    __syncthreads();
    for (int tl = 0; tl < CHUNK; tl++) {
        size_t t = (size_t)tbase + tl;
        float de = delta_q[t * QCH + dl];
        float uu = u_full[t * DI + d];
        float du = de * uu;
        float y = Dd * uu;
#pragma unroll
        for (int s = 0; s < 16; s++) {
            h[s] = __expf(de * As[s]) * h[s] + du * Bs[tl][s];
            y += h[s] * Cs[tl][s];
        }
        wg_ymod[t * DI + d] = y * wg_ymod[t * DI + d];   // y * w_gate, in place
    }
}

// ---------------------------------------------------------------------------
extern "C" void kernel_launch(void* const* d_in, const int* in_sizes, int n_in,
                              void* d_out, int out_size, void* d_ws, size_t ws_size,
                              hipStream_t stream)
{
    const float* x         = (const float*)d_in[0];
    const float* guidance  = (const float*)d_in[1];
    const float* in_proj_w = (const float*)d_in[2];
    const float* conv_w    = (const float*)d_in[3];
    const float* conv_b    = (const float*)d_in[4];
    const float* x_proj_w  = (const float*)d_in[5];
    const float* dt_proj_w = (const float*)d_in[6];
    const float* dt_proj_b = (const float*)d_in[7];
    const float* gg1_w     = (const float*)d_in[8];
    const float* gg1_b     = (const float*)d_in[9];
    const float* ln_g      = (const float*)d_in[10];
    const float* ln_b      = (const float*)d_in[11];
    const float* gg2_w     = (const float*)d_in[12];
    const float* gg2_b     = (const float*)d_in[13];
    const float* A_log     = (const float*)d_in[14];
    const float* Dp        = (const float*)d_in[15];
    const float* out_proj_w= (const float*)d_in[16];
    float* out = (float*)d_out;

    // ws: two N x 512 fp32 buffers = 256 MiB exactly.
    float* P1 = (float*)d_ws;                    // x_mod (scan u)
    float* P2 = P1 + (size_t)NTOK * DI;          // w_gate -> y_mod (in place)

    // d_out as pre-final scratch (final GEMM overwrites all).
    float* ob      = (float*)d_out;
    float* delta_q = ob;                                  // N x 128   (32 MiB)
    float* xdbl    = ob + (size_t)NTOK * QCH;             // N x 32    (8 MiB)
    float* h_end   = ob + (size_t)NTOK * (QCH + 32);      // 4 MiB
    float* Ssum    = h_end + (size_t)NCHUNK * QCH * DS;   // 0.25 MiB
    float* initS   = Ssum + (size_t)NCHUNK * QCH;         // 4 MiB
    // bf16 hi/lo packet buffers in the free tail of d_out:
    //   Wg  (gg2_w)      131072 packets = 2 MiB
    //   Wg2 (in_proj_w)   65536 packets = 1 MiB
    //   Wdt (dt_proj_w)   65536 packets = 1 MiB
    unsigned short* Wg  = (unsigned short*)(initS + (size_t)NCHUNK * QCH * DS);
    unsigned short* Wg2 = Wg  + (size_t)131072 * 8;
    unsigned short* Wdt = Wg2 + (size_t)65536 * 8;
    // Wout lives in P1's head (dead after the scans); written just-in-time.
    unsigned short* Wout = (unsigned short*)P1;

    // 0. W split-precision preps
    wprep_kernel<<<512, 256, 0, stream>>>(gg2_w, Wg);
    wprep_inproj<<<256, 256, 0, stream>>>(in_proj_w, Wg2);
    wprep_dt<<<256, 256, 0, stream>>>(dt_proj_w, Wdt);
    // 1. in_proj + conv + silu (bf16x3 MFMA) -> P1 = silu(conv(x_in)), P2 = silu(z)
    in_conv_mfma<<<NTOK / 64, 512, 0, stream>>>(
        x, Wg2, conv_w, conv_b, P1, P2);
    // 2. gates (barrier-free bf16x3 MFMA): P1 *= gate_in, P2 *= gate_out
    gates_mfma_kernel<<<NTOK / 64, 512, 0, stream>>>(
        guidance, gg1_w, gg1_b, ln_g, ln_b, Wg, gg2_b, P1, P2);
    // 3. xdbl = x_mod @ x_proj_w.T  (B|C)
    gemm_nt32<<<NTOK / 64, 256, 0, stream>>>(P1, x_proj_w, xdbl, DI, 32);
    // 4. per 128-channel quarter: delta MFMA GEMM + 3-pass scan
    for (int q = 0; q < 4; q++) {
        int dbase = q * QCH;
        dtp_mfma<<<NTOK / 64, 512, 0, stream>>>(
            P1, Wdt, dt_proj_b, dbase, delta_q);
        scan_pass1<<<NCHUNK, 128, 0, stream>>>(
            delta_q, P1, xdbl, A_log, dbase, h_end, Ssum);
        scan_pass2<<<(QCH * DS) / 256, 256, 0, stream>>>(
            h_end, Ssum, A_log, dbase, initS);
        scan_pass3<<<NCHUNK, 128, 0, stream>>>(
            delta_q, P1, xdbl, A_log, dbase, initS, Dp, P2);
    }
    // 5. out = y_mod @ out_proj_w.T (bf16x3 MFMA; Wout into dead P1 first)
    wprep_out<<<128, 256, 0, stream>>>(out_proj_w, Wout);
    outp_mfma<<<NTOK / 64, 512, 0, stream>>>(P2, Wout, out);
}

// Round 6
// 1794.933 us; speedup vs baseline: 2.5076x; 1.4357x over previous
//
#include <hip/hip_runtime.h>
#include <math.h>

#define NTOK 65536
#define DMODEL 256
#define DI 512
#define DS 16
#define CHUNK 128
#define NCHUNK (NTOK / CHUNK)   // 512
#define QCH 128                 // channels per scan quarter

typedef __bf16 bf16x8 __attribute__((ext_vector_type(8)));
typedef float  f32x4  __attribute__((ext_vector_type(4)));

__device__ __forceinline__ float sigf(float x) { return 1.0f / (1.0f + expf(-x)); }

// ---------------------------------------------------------------------------
// wprep_kernel: split the two used 512x512 blocks of gg2_w into hi/lo bf16,
// fragment packet order (verified round 1/2).
// ---------------------------------------------------------------------------
__global__ __launch_bounds__(256) void wprep_kernel(
    const float* gg2_w, unsigned short* Wg)
{
    int p = blockIdx.x * 256 + threadIdx.x;   // 0 .. 131071
    int lg = p & 3;
    int c  = (p >> 2) & 511;
    int hl = (p >> 11) & 1;
    int kc = (p >> 12) & 15;
    int gm = p >> 16;
    int row = gm * 1024 + c;
    const float* src = gg2_w + (size_t)row * 512 + kc * 32 + lg * 8;
    union { unsigned short u[8]; float4 f; } outv;
#pragma unroll
    for (int j = 0; j < 8; j++) {
        float x = src[j];
        __bf16 h = (__bf16)x;
        union { __bf16 b; unsigned short us; } cv;
        if (hl) cv.b = (__bf16)(x - (float)h); else cv.b = h;
        outv.u[j] = cv.us;
    }
    *(float4*)(Wg + (size_t)p * 8) = outv.f;
}

// ---------------------------------------------------------------------------
// wprep_inproj: split in_proj_w (1024 x 256), fragment order (verified r2).
// ---------------------------------------------------------------------------
__global__ __launch_bounds__(256) void wprep_inproj(
    const float* in_proj_w, unsigned short* Wg2)
{
    int p = blockIdx.x * 256 + threadIdx.x;   // 0 .. 65535
    int lg = p & 3;
    int c  = (p >> 2) & 511;
    int hl = (p >> 11) & 1;
    int kc = (p >> 12) & 7;
    int gm = p >> 15;
    const float* src = in_proj_w + (size_t)(gm * 512 + c) * 256 + kc * 32 + lg * 8;
    union { unsigned short u[8]; float4 f; } outv;
#pragma unroll
    for (int j = 0; j < 8; j++) {
        float x = src[j];
        __bf16 h = (__bf16)x;
        union { __bf16 b; unsigned short us; } cv;
        if (hl) cv.b = (__bf16)(x - (float)h); else cv.b = h;
        outv.u[j] = cv.us;
    }
    *(float4*)(Wg2 + (size_t)p * 8) = outv.f;
}

// ---------------------------------------------------------------------------
// wprep_dt: split dt_proj_w (512 x 512) into hi/lo bf16 packets, per-quarter.
// ---------------------------------------------------------------------------
__global__ __launch_bounds__(256) void wprep_dt(
    const float* dt_proj_w, unsigned short* Wdt)
{
    int p = blockIdx.x * 256 + threadIdx.x;   // 0 .. 65535
    int lg = p & 3;
    int c  = (p >> 2) & 127;
    int hl = (p >> 9) & 1;
    int kc = (p >> 10) & 15;
    int q  = p >> 14;
    const float* src = dt_proj_w + (size_t)(q * 128 + c) * 512 + kc * 32 + lg * 8;
    union { unsigned short u[8]; float4 f; } outv;
#pragma unroll
    for (int j = 0; j < 8; j++) {
        float x = src[j];
        __bf16 h = (__bf16)x;
        union { __bf16 b; unsigned short us; } cv;
        if (hl) cv.b = (__bf16)(x - (float)h); else cv.b = h;
        outv.u[j] = cv.us;
    }
    *(float4*)(Wdt + (size_t)p * 8) = outv.f;
}

// ---------------------------------------------------------------------------
// wprep_out: split out_proj_w (256 x 512) into hi/lo bf16 packets.
// Written into the (then-dead) head of P1 just before the final GEMM.
// ---------------------------------------------------------------------------
__global__ __launch_bounds__(256) void wprep_out(
    const float* out_proj_w, unsigned short* Wout)
{
    int p = blockIdx.x * 256 + threadIdx.x;   // 0 .. 32767
    int lg = p & 3;
    int c  = (p >> 2) & 255;
    int hl = (p >> 10) & 1;
    int kc = p >> 11;
    const float* src = out_proj_w + (size_t)c * 512 + kc * 32 + lg * 8;
    union { unsigned short u[8]; float4 f; } outv;
#pragma unroll
    for (int j = 0; j < 8; j++) {
        float x = src[j];
        __bf16 h = (__bf16)x;
        union { __bf16 b; unsigned short us; } cv;
        if (hl) cv.b = (__bf16)(x - (float)h); else cv.b = h;
        outv.u[j] = cv.us;
    }
    *(float4*)(Wout + (size_t)p * 8) = outv.f;
}

// ---------------------------------------------------------------------------
// in_conv_mfma: bf16x3 streaming-MFMA in_proj + conv + silu (round-3 verified)
// ---------------------------------------------------------------------------
#define MFMA_CHUNK(NFM, KC, WH, WL)                                           \
    _Pragma("unroll")                                                         \
    for (int fm = 0; fm < NFM; fm++) {                                        \
        int t = (fm < 4) ? (fm * 16 + lr) : (64 + lr);                        \
        int pidx = (t * 32 + (((KC) * 4 + lg) ^ (t & 7))) * 8;                \
        bf16x8 ah = *(const bf16x8*)&AhL[pidx];                               \
        bf16x8 al = *(const bf16x8*)&AlL[pidx];                               \
        _Pragma("unroll")                                                     \
        for (int fn = 0; fn < 4; fn++) {                                      \
            acc[fm][fn] = __builtin_amdgcn_mfma_f32_16x16x32_bf16(ah, WH[fn], acc[fm][fn], 0, 0, 0); \
            acc[fm][fn] = __builtin_amdgcn_mfma_f32_16x16x32_bf16(ah, WL[fn], acc[fm][fn], 0, 0, 0); \
            acc[fm][fn] = __builtin_amdgcn_mfma_f32_16x16x32_bf16(al, WH[fn], acc[fm][fn], 0, 0, 0); \
        }                                                                     \
    }

__global__ __launch_bounds__(512, 2) void in_conv_mfma(
    const float* x, const unsigned short* Wg2, const float* conv_w,
    const float* conv_b, float* P1, float* P2)
{
    __shared__ __align__(16) unsigned short smem[2 * 80 * 256];  // 80 KiB
    unsigned short* AhL = smem;
    unsigned short* AlL = smem + 80 * 256;
    float* xs = (float*)smem;          // repurposed: [8 waves][68][33] fp32

    const int tid = threadIdx.x;
    const int row0 = blockIdx.x * 64;
    const int l  = tid & 63;
    const int wn = tid >> 6;           // wave id / col-slice
    const int lr = l & 15;
    const int lg = l >> 4;

    // ---- Phase A: stage x split hi/lo (rows 0..63 main, 64..67 halo, rest 0)
    for (int i = tid; i < 80 * 32; i += 512) {
        int t = i >> 5, k8 = i & 31;
        float xv[8];
#pragma unroll
        for (int j = 0; j < 8; j++) xv[j] = 0.f;
        if (t < 68) {
            int gr = (t < 64) ? (row0 + t) : (row0 - 68 + t);
            if (gr >= 0) {
                float4 a0 = *(const float4*)(x + (size_t)gr * 256 + k8 * 8);
                float4 a1 = *(const float4*)(x + (size_t)gr * 256 + k8 * 8 + 4);
                xv[0]=a0.x; xv[1]=a0.y; xv[2]=a0.z; xv[3]=a0.w;
                xv[4]=a1.x; xv[5]=a1.y; xv[6]=a1.z; xv[7]=a1.w;
            }
        }
        bf16x8 ho, lo;
#pragma unroll
        for (int j = 0; j < 8; j++) {
            __bf16 hh = (__bf16)xv[j];
            ho[j] = hh;
            lo[j] = (__bf16)(xv[j] - (float)hh);
        }
        int pidx = (t * 32 + (k8 ^ (t & 7))) * 8;
        *(bf16x8*)&AhL[pidx] = ho;
        *(bf16x8*)&AlL[pidx] = lo;
    }
    __syncthreads();

    auto loadW = [&](int gm, int kc, bf16x8 (&wh)[4], bf16x8 (&wl)[4]) {
        const unsigned short* bh = Wg2 + (size_t)(((gm * 8 + kc) * 2 + 0) * 2048) * 8;
        const unsigned short* bl = Wg2 + (size_t)(((gm * 8 + kc) * 2 + 1) * 2048) * 8;
        const int pk = (wn * 64 + lr) * 4 + lg;
#pragma unroll
        for (int fn = 0; fn < 4; fn++) {
            wh[fn] = *(const bf16x8*)(bh + (size_t)(pk + fn * 64) * 8);
            wl[fn] = *(const bf16x8*)(bl + (size_t)(pk + fn * 64) * 8);
        }
    };

    // ---- z half (gm=1): 4 fm tiles, direct silu epilogue ----
    {
        f32x4 acc[4][4];
#pragma unroll
        for (int fm = 0; fm < 4; fm++)
#pragma unroll
            for (int fn = 0; fn < 4; fn++)
                acc[fm][fn] = (f32x4){0.f, 0.f, 0.f, 0.f};
        bf16x8 whA[4], wlA[4], whB[4], wlB[4];
        loadW(1, 0, whA, wlA);
#pragma unroll
        for (int kc = 0; kc < 8; kc += 2) {
            loadW(1, kc + 1, whB, wlB);
            MFMA_CHUNK(4, kc, whA, wlA)
            if (kc + 2 < 8) loadW(1, kc + 2, whA, wlA);
            MFMA_CHUNK(4, kc + 1, whB, wlB)
        }
#pragma unroll
        for (int fm = 0; fm < 4; fm++)
#pragma unroll
            for (int fn = 0; fn < 4; fn++) {
                int col = wn * 64 + fn * 16 + lr;
#pragma unroll
                for (int q = 0; q < 4; q++) {
                    int r = row0 + fm * 16 + lg * 4 + q;
                    float vz = acc[fm][fn][q];
                    P2[(size_t)r * 512 + col] = vz * sigf(vz);
                }
            }
    }

    // ---- x_in half (gm=0): 5 fm tiles (halo), conv epilogue ----
    {
        f32x4 acc[5][4];
#pragma unroll
        for (int fm = 0; fm < 5; fm++)
#pragma unroll
            for (int fn = 0; fn < 4; fn++)
                acc[fm][fn] = (f32x4){0.f, 0.f, 0.f, 0.f};
        bf16x8 whA[4], wlA[4], whB[4], wlB[4];
        loadW(0, 0, whA, wlA);
#pragma unroll
        for (int kc = 0; kc < 8; kc += 2) {
            loadW(0, kc + 1, whB, wlB);
            MFMA_CHUNK(5, kc, whA, wlA)
            if (kc + 2 < 8) loadW(0, kc + 2, whA, wlA);
            MFMA_CHUNK(5, kc + 1, whB, wlB)
        }

        __syncthreads();                       // all waves done reading A-LDS
        float* xsw = xs + wn * (68 * 33);      // per-wave slab (wave-private)
        const int c_local = l & 31;
        const int rbase = (l >> 5) * 32;
#pragma unroll
        for (int h = 0; h < 2; h++) {
            if (h) __syncthreads();            // uniform; protects slab reuse
#pragma unroll
            for (int fm = 0; fm < 5; fm++)
#pragma unroll
                for (int ff = 0; ff < 2; ff++) {
                    int fn = h * 2 + ff;
#pragma unroll
                    for (int q = 0; q < 4; q++) {
                        if (fm < 4) {
                            int rr = 4 + fm * 16 + lg * 4 + q;
                            xsw[rr * 33 + ff * 16 + lr] = acc[fm][fn][q];
                        } else if (lg == 0) {
                            xsw[q * 33 + ff * 16 + lr] = acc[fm][fn][q];
                        }
                    }
                }
            asm volatile("s_waitcnt lgkmcnt(0)" ::: "memory");
            int cg = wn * 64 + h * 32 + c_local;
            float w0 = conv_w[cg * 4 + 0], w1 = conv_w[cg * 4 + 1];
            float w2 = conv_w[cg * 4 + 2], w3 = conv_w[cg * 4 + 3];
            float cb = conv_b[cg];
            float s0 = xsw[(rbase + 1) * 33 + c_local];
            float s1 = xsw[(rbase + 2) * 33 + c_local];
            float s2 = xsw[(rbase + 3) * 33 + c_local];
#pragma unroll
            for (int i = 0; i < 32; i++) {
                float s3 = xsw[(rbase + 4 + i) * 33 + c_local];
                float cv = cb + w0 * s0 + w1 * s1 + w2 * s2 + w3 * s3;
                cv = cv * sigf(cv);
                P1[(size_t)(row0 + rbase + i) * 512 + cg] = cv;
                s0 = s1; s1 = s2; s2 = s3;
            }
        }
    }
}

// ---------------------------------------------------------------------------
// gates_mfma_kernel v2: barrier-free streaming MFMA. (round-2 verified)
// ---------------------------------------------------------------------------
__global__ __launch_bounds__(512, 2) void gates_mfma_kernel(
    const float* guidance, const float* gg1_w, const float* gg1_b,
    const float* ln_g, const float* ln_b,
    const unsigned short* Wg, const float* gg2_b,
    float* P1, float* P2)
{
    __shared__ unsigned short AhL[64 * 512];   // 64 KiB  [tok][k] swizzled
    __shared__ unsigned short AlL[64 * 512];   // 64 KiB
    __shared__ float red_s[64][9], red_q[64][9];

    const int tid = threadIdx.x;
    const int tok = tid & 63;
    const int o   = tid >> 6;        // 0..7 == wave id
    const int row0 = blockIdx.x * 64;

    float g0 = guidance[(size_t)(row0 + tok) * 3 + 0];
    float g1 = guidance[(size_t)(row0 + tok) * 3 + 1];
    float g2 = guidance[(size_t)(row0 + tok) * 3 + 2];
    float v[64];
    float sum = 0.f, sumsq = 0.f;
#pragma unroll
    for (int m = 0; m < 8; m++)
#pragma unroll
        for (int jj = 0; jj < 8; jj++) {
            int d = m * 64 + o * 8 + jj;
            float t = gg1_w[d * 3 + 0] * g0 + gg1_w[d * 3 + 1] * g1 +
                      gg1_w[d * 3 + 2] * g2 + gg1_b[d];
            v[m * 8 + jj] = t;
            sum += t; sumsq += t * t;
        }
    red_s[tok][o] = sum; red_q[tok][o] = sumsq;
    __syncthreads();
    sum = 0.f; sumsq = 0.f;
#pragma unroll
    for (int oo = 0; oo < 8; oo++) { sum += red_s[tok][oo]; sumsq += red_q[tok][oo]; }
    float mu = sum * (1.f / 512.f);
    float var = fmaxf(sumsq * (1.f / 512.f) - mu * mu, 0.f);
    float rstd = 1.f / sqrtf(var + 1e-5f);
#pragma unroll
    for (int m = 0; m < 8; m++) {
        bf16x8 hoct, loct;
#pragma unroll
        for (int jj = 0; jj < 8; jj++) {
            int d = m * 64 + o * 8 + jj;
            float t = (v[m * 8 + jj] - mu) * rstd * ln_g[d] + ln_b[d];
            t = 0.5f * t * (1.f + erff(t * 0.70710678118654752440f));
            __bf16 h = (__bf16)t;
            hoct[jj] = h;
            loct[jj] = (__bf16)(t - (float)h);
        }
        int pidx = ((tok * 64 + (m * 8 + o)) ^ (tok & 7)) * 8;
        *(bf16x8*)&AhL[pidx] = hoct;
        *(bf16x8*)&AlL[pidx] = loct;
    }
    __syncthreads();     // the ONLY barrier before Phase B

    const int l  = tid & 63;
    const int wn = tid >> 6;
    const int lr = l & 15;
    const int lg = l >> 4;

    for (int gm = 0; gm < 2; gm++) {
        f32x4 acc[4][4];
#pragma unroll
        for (int fm = 0; fm < 4; fm++)
#pragma unroll
            for (int fn = 0; fn < 4; fn++)
                acc[fm][fn] = (f32x4){0.f, 0.f, 0.f, 0.f};

        bf16x8 whA[4], wlA[4], whB[4], wlB[4];

        auto loadW = [&](int kc, bf16x8 (&wh)[4], bf16x8 (&wl)[4]) {
            const unsigned short* bh = Wg + (size_t)(((gm * 16 + kc) * 2 + 0) * 2048) * 8;
            const unsigned short* bl = Wg + (size_t)(((gm * 16 + kc) * 2 + 1) * 2048) * 8;
            int pk = (wn * 64 + lr) * 4 + lg;
#pragma unroll
            for (int fn = 0; fn < 4; fn++) {
                wh[fn] = *(const bf16x8*)(bh + (size_t)(pk + fn * 64) * 8);
                wl[fn] = *(const bf16x8*)(bl + (size_t)(pk + fn * 64) * 8);
            }
        };
        auto doChunk = [&](int kc, const bf16x8 (&wh)[4], const bf16x8 (&wl)[4]) {
#pragma unroll
            for (int fm = 0; fm < 4; fm++) {
                int t = fm * 16 + lr;
                int pidx = ((t * 64 + kc * 4 + lg) ^ (lr & 7)) * 8;
                bf16x8 ah = *(const bf16x8*)&AhL[pidx];
                bf16x8 al = *(const bf16x8*)&AlL[pidx];
#pragma unroll
                for (int fn = 0; fn < 4; fn++) {
                    acc[fm][fn] = __builtin_amdgcn_mfma_f32_16x16x32_bf16(
                        ah, wh[fn], acc[fm][fn], 0, 0, 0);
                    acc[fm][fn] = __builtin_amdgcn_mfma_f32_16x16x32_bf16(
                        ah, wl[fn], acc[fm][fn], 0, 0, 0);
                    acc[fm][fn] = __builtin_amdgcn_mfma_f32_16x16x32_bf16(
                        al, wh[fn], acc[fm][fn], 0, 0, 0);
                }
            }
        };

        loadW(0, whA, wlA);
        for (int kc = 0; kc < 16; kc += 2) {
            loadW(kc + 1, whB, wlB);
            doChunk(kc, whA, wlA);
            if (kc + 2 < 16) loadW(kc + 2, whA, wlA);
            doChunk(kc + 1, whB, wlB);
        }

        float* P = gm ? P2 : P1;
        const float* bias = gg2_b + gm * 1024;
#pragma unroll
        for (int fm = 0; fm < 4; fm++)
#pragma unroll
            for (int fn = 0; fn < 4; fn++) {
                int col = wn * 64 + fn * 16 + lr;
                float b = bias[col];
#pragma unroll
                for (int q = 0; q < 4; q++) {
                    int r = row0 + fm * 16 + lg * 4 + q;
                    size_t idx = (size_t)r * 512 + col;
                    P[idx] *= sigf(acc[fm][fn][q] + b);
                }
            }
    }
}

// ---------------------------------------------------------------------------
// dtp_mfma: delta quarter = softplus(P1 @ dt_proj_w[q].T + b), bf16x3 MFMA.
// (round-4 verified)
// ---------------------------------------------------------------------------
__global__ __launch_bounds__(512, 2) void dtp_mfma(
    const float* A, const unsigned short* Wdt, const float* bias,
    int dbase, float* delta_q)
{
    __shared__ __align__(16) unsigned short AhL[64 * 512];  // 64 KiB
    __shared__ __align__(16) unsigned short AlL[64 * 512];  // 64 KiB
    const int tid = threadIdx.x;
    const int row0 = blockIdx.x * 64;

    for (int i = tid; i < 64 * 64; i += 512) {
        int t = i >> 6, k8 = i & 63;
        const float* src = A + (size_t)(row0 + t) * 512 + k8 * 8;
        float4 a0 = *(const float4*)src, a1 = *(const float4*)(src + 4);
        float xv[8] = {a0.x, a0.y, a0.z, a0.w, a1.x, a1.y, a1.z, a1.w};
        bf16x8 ho, lo;
#pragma unroll
        for (int j = 0; j < 8; j++) {
            __bf16 hh = (__bf16)xv[j];
            ho[j] = hh;
            lo[j] = (__bf16)(xv[j] - (float)hh);
        }
        int pidx = (t * 64 + (k8 ^ (t & 7))) * 8;
        *(bf16x8*)&AhL[pidx] = ho;
        *(bf16x8*)&AlL[pidx] = lo;
    }
    __syncthreads();

    const int l  = tid & 63;
    const int wv = tid >> 6;
    const int wr = wv >> 2;          // 0..1  token half (32 rows)
    const int wc = wv & 3;           // 0..3  col quarter (32 cols)
    const int lr = l & 15;
    const int lg = l >> 4;
    const unsigned short* Wq = Wdt + (size_t)(dbase >> 7) * 16384 * 8;

    f32x4 acc[2][2];
#pragma unroll
    for (int fm = 0; fm < 2; fm++)
#pragma unroll
        for (int fn = 0; fn < 2; fn++)
            acc[fm][fn] = (f32x4){0.f, 0.f, 0.f, 0.f};

    bf16x8 whA[2], wlA[2], whB[2], wlB[2];
    auto loadW = [&](int kc, bf16x8 (&wh)[2], bf16x8 (&wl)[2]) {
        const unsigned short* bh = Wq + (size_t)((kc * 2 + 0) * 512) * 8;
        const unsigned short* bl = Wq + (size_t)((kc * 2 + 1) * 512) * 8;
        int pk = (wc * 32 + lr) * 4 + lg;
#pragma unroll
        for (int fn = 0; fn < 2; fn++) {
            wh[fn] = *(const bf16x8*)(bh + (size_t)(pk + fn * 64) * 8);
            wl[fn] = *(const bf16x8*)(bl + (size_t)(pk + fn * 64) * 8);
        }
    };
    auto doChunk = [&](int kc, const bf16x8 (&wh)[2], const bf16x8 (&wl)[2]) {
#pragma unroll
        for (int fm = 0; fm < 2; fm++) {
            int t = wr * 32 + fm * 16 + lr;
            int pidx = (t * 64 + ((kc * 4 + lg) ^ (t & 7))) * 8;
            bf16x8 ah = *(const bf16x8*)&AhL[pidx];
            bf16x8 al = *(const bf16x8*)&AlL[pidx];
#pragma unroll
            for (int fn = 0; fn < 2; fn++) {
                acc[fm][fn] = __builtin_amdgcn_mfma_f32_16x16x32_bf16(
                    ah, wh[fn], acc[fm][fn], 0, 0, 0);
                acc[fm][fn] = __builtin_amdgcn_mfma_f32_16x16x32_bf16(
                    ah, wl[fn], acc[fm][fn], 0, 0, 0);
                acc[fm][fn] = __builtin_amdgcn_mfma_f32_16x16x32_bf16(
                    al, wh[fn], acc[fm][fn], 0, 0, 0);
            }
        }
    };

    loadW(0, whA, wlA);
    for (int kc = 0; kc < 16; kc += 2) {
        loadW(kc + 1, whB, wlB);
        doChunk(kc, whA, wlA);
        if (kc + 2 < 16) loadW(kc + 2, whA, wlA);
        doChunk(kc + 1, whB, wlB);
    }

#pragma unroll
    for (int fm = 0; fm < 2; fm++)
#pragma unroll
        for (int fn = 0; fn < 2; fn++) {
            int col = wc * 32 + fn * 16 + lr;
            float b = bias[dbase + col];
#pragma unroll
            for (int q = 0; q < 4; q++) {
                int r = row0 + wr * 32 + fm * 16 + lg * 4 + q;
                float s = acc[fm][fn][q] + b;
                delta_q[(size_t)r * 128 + col] =
                    fmaxf(s, 0.f) + log1pf(expf(-fabsf(s)));
            }
        }
}

// ---------------------------------------------------------------------------
// outp_mfma: out = P2 @ out_proj_w.T (256 cols), bf16x3 MFMA. (r4 verified)
// ---------------------------------------------------------------------------
__global__ __launch_bounds__(512, 2) void outp_mfma(
    const float* A, const unsigned short* Wout, float* out)
{
    __shared__ __align__(16) unsigned short AhL[64 * 512];  // 64 KiB
    __shared__ __align__(16) unsigned short AlL[64 * 512];  // 64 KiB
    const int tid = threadIdx.x;
    const int row0 = blockIdx.x * 64;

    for (int i = tid; i < 64 * 64; i += 512) {
        int t = i >> 6, k8 = i & 63;
        const float* src = A + (size_t)(row0 + t) * 512 + k8 * 8;
        float4 a0 = *(const float4*)src, a1 = *(const float4*)(src + 4);
        float xv[8] = {a0.x, a0.y, a0.z, a0.w, a1.x, a1.y, a1.z, a1.w};
        bf16x8 ho, lo;
#pragma unroll
        for (int j = 0; j < 8; j++) {
            __bf16 hh = (__bf16)xv[j];
            ho[j] = hh;
            lo[j] = (__bf16)(xv[j] - (float)hh);
        }
        int pidx = (t * 64 + (k8 ^ (t & 7))) * 8;
        *(bf16x8*)&AhL[pidx] = ho;
        *(bf16x8*)&AlL[pidx] = lo;
    }
    __syncthreads();

    const int l  = tid & 63;
    const int wv = tid >> 6;
    const int wr = wv >> 2;          // 0..1  token half (32 rows)
    const int wc = wv & 3;           // 0..3  col slice (64 cols)
    const int lr = l & 15;
    const int lg = l >> 4;

    f32x4 acc[2][4];
#pragma unroll
    for (int fm = 0; fm < 2; fm++)
#pragma unroll
        for (int fn = 0; fn < 4; fn++)
            acc[fm][fn] = (f32x4){0.f, 0.f, 0.f, 0.f};

    bf16x8 whA[4], wlA[4], whB[4], wlB[4];
    auto loadW = [&](int kc, bf16x8 (&wh)[4], bf16x8 (&wl)[4]) {
        const unsigned short* bh = Wout + (size_t)((kc * 2 + 0) * 1024) * 8;
        const unsigned short* bl = Wout + (size_t)((kc * 2 + 1) * 1024) * 8;
        int pk = (wc * 64 + lr) * 4 + lg;
#pragma unroll
        for (int fn = 0; fn < 4; fn++) {
            wh[fn] = *(const bf16x8*)(bh + (size_t)(pk + fn * 64) * 8);
            wl[fn] = *(const bf16x8*)(bl + (size_t)(pk + fn * 64) * 8);
        }
    };
    auto doChunk = [&](int kc, const bf16x8 (&wh)[4], const bf16x8 (&wl)[4]) {
#pragma unroll
        for (int fm = 0; fm < 2; fm++) {
            int t = wr * 32 + fm * 16 + lr;
            int pidx = (t * 64 + ((kc * 4 + lg) ^ (t & 7))) * 8;
            bf16x8 ah = *(const bf16x8*)&AhL[pidx];
            bf16x8 al = *(const bf16x8*)&AlL[pidx];
#pragma unroll
            for (int fn = 0; fn < 4; fn++) {
                acc[fm][fn] = __builtin_amdgcn_mfma_f32_16x16x32_bf16(
                    ah, wh[fn], acc[fm][fn], 0, 0, 0);
                acc[fm][fn] = __builtin_amdgcn_mfma_f32_16x16x32_bf16(
                    ah, wl[fn], acc[fm][fn], 0, 0, 0);
                acc[fm][fn] = __builtin_amdgcn_mfma_f32_16x16x32_bf16(
                    al, wh[fn], acc[fm][fn], 0, 0, 0);
            }
        }
    };

    loadW(0, whA, wlA);
    for (int kc = 0; kc < 16; kc += 2) {
        loadW(kc + 1, whB, wlB);
        doChunk(kc, whA, wlA);
        if (kc + 2 < 16) loadW(kc + 2, whA, wlA);
        doChunk(kc + 1, whB, wlB);
    }

#pragma unroll
    for (int fm = 0; fm < 2; fm++)
#pragma unroll
        for (int fn = 0; fn < 4; fn++) {
            int col = wc * 64 + fn * 16 + lr;
#pragma unroll
            for (int q = 0; q < 4; q++) {
                int r = row0 + wr * 32 + fm * 16 + lg * 4 + q;
                out[(size_t)r * 256 + col] = acc[fm][fn][q];
            }
        }
}

// ---------------------------------------------------------------------------
// Small GEMM for x_proj (32 cols), 256 threads (round-5 structure).
// ---------------------------------------------------------------------------
__global__ __launch_bounds__(256) void gemm_nt32(
    const float* A, const float* W, float* out0, int K, int ldo)
{
    __shared__ float As[16][65];
    __shared__ float Ws[16][33];
    const int tid = threadIdx.x;
    const int row0 = blockIdx.x * 64;
    const int tr = (tid / 16) * 4;
    const int tc = (tid % 16) * 2;
    float acc[4][2];
#pragma unroll
    for (int i = 0; i < 4; i++) { acc[i][0] = 0.f; acc[i][1] = 0.f; }
    for (int k0 = 0; k0 < K; k0 += 16) {
        __syncthreads();
        for (int i = tid; i < 64 * 16; i += 256) {
            int m = i / 16, k = i % 16;
            As[k][m] = A[(size_t)(row0 + m) * K + k0 + k];
        }
        for (int i = tid; i < 32 * 16; i += 256) {
            int n = i / 16, k = i % 16;
            Ws[k][n] = W[(size_t)n * K + k0 + k];
        }
        __syncthreads();
#pragma unroll
        for (int kk = 0; kk < 16; kk++) {
            float a[4], b[2];
#pragma unroll
            for (int i = 0; i < 4; i++) a[i] = As[kk][tr + i];
            b[0] = Ws[kk][tc]; b[1] = Ws[kk][tc + 1];
#pragma unroll
            for (int i = 0; i < 4; i++) { acc[i][0] += a[i] * b[0]; acc[i][1] += a[i] * b[1]; }
        }
    }
#pragma unroll
    for (int i = 0; i < 4; i++) {
        int r = row0 + tr + i;
        out0[(size_t)r * ldo + tc] = acc[i][0];
        out0[(size_t)r * ldo + tc + 1] = acc[i][1];
    }
}

// ---------------------------------------------------------------------------
// Selective scan, state-split: 256 threads/block; lane pair (2k,2k+1) shares
// channel dl = tid>>1, each handles 8 of 16 states. y-reduce via shfl_xor(1)
// (same wave). Doubles waves/SIMD and halves the per-token dependent chain.
// ---------------------------------------------------------------------------
__global__ __launch_bounds__(256) void scan_pass1(
    const float* delta_q, const float* u_full, const float* xdbl,
    const float* A_log, int dbase, float* h_end, float* Ssum)
{
    int c = blockIdx.x;
    int tid = threadIdx.x;
    int dl = tid >> 1;
    int sh = (tid & 1) * 8;
    int d = dbase + dl;
    float As[8];
#pragma unroll
    for (int s = 0; s < 8; s++) As[s] = -expf(A_log[d * 16 + sh + s]);
    float h[8];
#pragma unroll
    for (int s = 0; s < 8; s++) h[s] = 0.f;
    float S = 0.f;
    __shared__ float Bs[CHUNK][17];
    int tbase = c * CHUNK;
    for (int i = tid; i < CHUNK * 16; i += 256) {
        int r = i >> 4, s = i & 15;
        Bs[r][s] = xdbl[(size_t)(tbase + r) * 32 + s];
    }
    __syncthreads();
    for (int tl = 0; tl < CHUNK; tl++) {
        size_t t = (size_t)tbase + tl;
        float de = delta_q[t * QCH + dl];
        float uu = u_full[t * DI + d];
        float du = de * uu;
        S += de;
#pragma unroll
        for (int s = 0; s < 8; s++)
            h[s] = __expf(de * As[s]) * h[s] + du * Bs[tl][sh + s];
    }
    size_t base = ((size_t)c * QCH + dl) * 16 + sh;
#pragma unroll
    for (int s = 0; s < 8; s++) h_end[base + s] = h[s];
    if ((tid & 1) == 0) Ssum[(size_t)c * QCH + dl] = S;
}

// ---------------------------------------------------------------------------
// scan_pass2 (parallel): recurrence carry' = P*carry + h is associative under
// (P1,H1)∘(P2,H2) = (P1*P2, P2*H1 + H2). Three phases:
//   2a: per-16-chunk-group aggregates (65536 threads, 16 iters)
//   2b: serial scan over 32 group aggregates (2048 threads, 32 iters, L2-hot)
//   2c: replay within groups writing initS (65536 threads, 16 iters)
// ---------------------------------------------------------------------------
#define GRP 16
#define NGRP (NCHUNK / GRP)   // 32

__global__ __launch_bounds__(256) void scan_pass2a(
    const float* h_end, const float* Ssum, const float* A_log, int dbase,
    float* Pagg, float* Hagg)
{
    int idx = blockIdx.x * 256 + threadIdx.x;   // 0..2047
    int g = blockIdx.y;                         // 0..31
    int dl = idx >> 4;
    float As = -expf(A_log[(dbase + dl) * 16 + (idx & 15)]);
    float P = 1.f, H = 0.f;
    for (int c = g * GRP; c < g * GRP + GRP; c++) {
        float Pc = __expf(As * Ssum[(size_t)c * QCH + dl]);
        H = Pc * H + h_end[(size_t)c * 2048 + idx];
        P *= Pc;
    }
    Pagg[g * 2048 + idx] = P;
    Hagg[g * 2048 + idx] = H;
}

__global__ __launch_bounds__(256) void scan_pass2b(
    const float* Pagg, const float* Hagg, float* Ginit)
{
    int idx = blockIdx.x * 256 + threadIdx.x;   // 0..2047
    float carry = 0.f;
    for (int g = 0; g < NGRP; g++) {
        Ginit[g * 2048 + idx] = carry;
        carry = Pagg[g * 2048 + idx] * carry + Hagg[g * 2048 + idx];
    }
}

__global__ __launch_bounds__(256) void scan_pass2c(
    const float* h_end, const float* Ssum, const float* A_log, int dbase,
    const float* Ginit, float* initS)
{
    int idx = blockIdx.x * 256 + threadIdx.x;   // 0..2047
    int g = blockIdx.y;                         // 0..31
    int dl = idx >> 4;
    float As = -expf(A_log[(dbase + dl) * 16 + (idx & 15)]);
    float carry = Ginit[g * 2048 + idx];
    for (int c = g * GRP; c < g * GRP + GRP; c++) {
        initS[(size_t)c * 2048 + idx] = carry;
        float Pc = __expf(As * Ssum[(size_t)c * QCH + dl]);
        carry = Pc * carry + h_end[(size_t)c * 2048 + idx];
    }
}

__global__ __launch_bounds__(256) void scan_pass3(
    const float* delta_q, const float* u_full, const float* xdbl,
    const float* A_log, int dbase, const float* initS, const float* Dp,
    float* wg_ymod)
{
    int c = blockIdx.x;
    int tid = threadIdx.x;
    int dl = tid >> 1;
    int sh = (tid & 1) * 8;
    int d = dbase + dl;
    float As[8];
#pragma unroll
    for (int s = 0; s < 8; s++) As[s] = -expf(A_log[d * 16 + sh + s]);
    float h[8];
#pragma unroll
    for (int s = 0; s < 8; s++)
        h[s] = initS[((size_t)c * QCH + dl) * 16 + sh + s];
    float Dd = Dp[d];
    __shared__ float Bs[CHUNK][17];
    __shared__ float Cs[CHUNK][17];
    int tbase = c * CHUNK;
    for (int i = tid; i < CHUNK * 16; i += 256) {
        int r = i >> 4, s = i & 15;
        Bs[r][s] = xdbl[(size_t)(tbase + r) * 32 + s];
        Cs[r][s] = xdbl[(size_t)(tbase + r) * 32 + 16 + s];
    }
    __syncthreads();
    for (int tl = 0; tl < CHUNK; tl++) {
        size_t t = (size_t)tbase + tl;
        float de = delta_q[t * QCH + dl];
        float uu = u_full[t * DI + d];
        float du = de * uu;
        float y = 0.f;
#pragma unroll
        for (int s = 0; s < 8; s++) {
            h[s] = __expf(de * As[s]) * h[s] + du * Bs[tl][sh + s];
            y += h[s] * Cs[tl][sh + s];
        }
        y += __shfl_xor(y, 1);
        if ((tid & 1) == 0)
            wg_ymod[t * DI + d] = (y + Dd * uu) * wg_ymod[t * DI + d];
    }
}

// ---------------------------------------------------------------------------
extern "C" void kernel_launch(void* const* d_in, const int* in_sizes, int n_in,
                              void* d_out, int out_size, void* d_ws, size_t ws_size,
                              hipStream_t stream)
{
    const float* x         = (const float*)d_in[0];
    const float* guidance  = (const float*)d_in[1];
    const float* in_proj_w = (const float*)d_in[2];
    const float* conv_w    = (const float*)d_in[3];
    const float* conv_b    = (const float*)d_in[4];
    const float* x_proj_w  = (const float*)d_in[5];
    const float* dt_proj_w = (const float*)d_in[6];
    const float* dt_proj_b = (const float*)d_in[7];
    const float* gg1_w     = (const float*)d_in[8];
    const float* gg1_b     = (const float*)d_in[9];
    const float* ln_g      = (const float*)d_in[10];
    const float* ln_b      = (const float*)d_in[11];
    const float* gg2_w     = (const float*)d_in[12];
    const float* gg2_b     = (const float*)d_in[13];
    const float* A_log     = (const float*)d_in[14];
    const float* Dp        = (const float*)d_in[15];
    const float* out_proj_w= (const float*)d_in[16];
    float* out = (float*)d_out;

    // ws: two N x 512 fp32 buffers = 256 MiB exactly.
    float* P1 = (float*)d_ws;                    // x_mod (scan u)
    float* P2 = P1 + (size_t)NTOK * DI;          // w_gate -> y_mod (in place)

    // d_out as pre-final scratch (final GEMM overwrites all).
    float* ob      = (float*)d_out;
    float* delta_q = ob;                                  // N x 128   (32 MiB)
    float* xdbl    = ob + (size_t)NTOK * QCH;             // N x 32    (8 MiB)
    float* h_end   = ob + (size_t)NTOK * (QCH + 32);      // 4 MiB
    float* Ssum    = h_end + (size_t)NCHUNK * QCH * DS;   // 0.25 MiB
    float* initS   = Ssum + (size_t)NCHUNK * QCH;         // 4 MiB
    // bf16 hi/lo packet buffers + pass2 aggregates in the free tail of d_out:
    unsigned short* Wg  = (unsigned short*)(initS + (size_t)NCHUNK * QCH * DS);
    unsigned short* Wg2 = Wg  + (size_t)131072 * 8;
    unsigned short* Wdt = Wg2 + (size_t)65536 * 8;
    float* Pagg  = (float*)(Wdt + (size_t)65536 * 8);     // 32x2048 (256 KB)
    float* Hagg  = Pagg + NGRP * 2048;                    // 256 KB
    float* Ginit = Hagg + NGRP * 2048;                    // 256 KB
    // Wout lives in P1's head (dead after the scans); written just-in-time.
    unsigned short* Wout = (unsigned short*)P1;

    // 0. W split-precision preps
    wprep_kernel<<<512, 256, 0, stream>>>(gg2_w, Wg);
    wprep_inproj<<<256, 256, 0, stream>>>(in_proj_w, Wg2);
    wprep_dt<<<256, 256, 0, stream>>>(dt_proj_w, Wdt);
    // 1. in_proj + conv + silu (bf16x3 MFMA) -> P1 = silu(conv(x_in)), P2 = silu(z)
    in_conv_mfma<<<NTOK / 64, 512, 0, stream>>>(
        x, Wg2, conv_w, conv_b, P1, P2);
    // 2. gates (barrier-free bf16x3 MFMA): P1 *= gate_in, P2 *= gate_out
    gates_mfma_kernel<<<NTOK / 64, 512, 0, stream>>>(
        guidance, gg1_w, gg1_b, ln_g, ln_b, Wg, gg2_b, P1, P2);
    // 3. xdbl = x_mod @ x_proj_w.T  (B|C)
    gemm_nt32<<<NTOK / 64, 256, 0, stream>>>(P1, x_proj_w, xdbl, DI, 32);
    // 4. per 128-channel quarter: delta MFMA GEMM + chunked scan
    for (int q = 0; q < 4; q++) {
        int dbase = q * QCH;
        dtp_mfma<<<NTOK / 64, 512, 0, stream>>>(
            P1, Wdt, dt_proj_b, dbase, delta_q);
        scan_pass1<<<NCHUNK, 256, 0, stream>>>(
            delta_q, P1, xdbl, A_log, dbase, h_end, Ssum);
        scan_pass2a<<<dim3(8, NGRP), 256, 0, stream>>>(
            h_end, Ssum, A_log, dbase, Pagg, Hagg);
        scan_pass2b<<<8, 256, 0, stream>>>(Pagg, Hagg, Ginit);
        scan_pass2c<<<dim3(8, NGRP), 256, 0, stream>>>(
            h_end, Ssum, A_log, dbase, Ginit, initS);
        scan_pass3<<<NCHUNK, 256, 0, stream>>>(
            delta_q, P1, xdbl, A_log, dbase, initS, Dp, P2);
    }
    // 5. out = y_mod @ out_proj_w.T (bf16x3 MFMA; Wout into dead P1 first)
    wprep_out<<<128, 256, 0, stream>>>(out_proj_w, Wout);
    outp_mfma<<<NTOK / 64, 512, 0, stream>>>(P2, Wout, out);
}